// Round 1
// baseline (2502.883 us; speedup 1.0000x reference)
//
#include <hip/hip_runtime.h>
#include <math.h>

#define SEQ   2048
#define HID   1024
#define NHEAD 16
#define HDIM  64
#define NEXP  8
#define IDIM  4096
#define CAPE  1024
#define QKVW  3072

#define BM 128
#define BN 64
#define BKC 16

// ---------------- RMSNorm ----------------
__global__ __launch_bounds__(256) void k_rmsnorm(const float* __restrict__ x,
                                                 const float* __restrict__ w,
                                                 float* __restrict__ out) {
  const int row = blockIdx.x, t = threadIdx.x;
  float4 v = ((const float4*)(x + (size_t)row * HID))[t];
  float ss = v.x*v.x + v.y*v.y + v.z*v.z + v.w*v.w;
  #pragma unroll
  for (int off = 32; off; off >>= 1) ss += __shfl_down(ss, off);
  __shared__ float red[4];
  if ((t & 63) == 0) red[t >> 6] = ss;
  __syncthreads();
  const float inv = rsqrtf((red[0] + red[1] + red[2] + red[3]) * (1.0f / HID) + 1e-6f);
  float4 wv = ((const float4*)w)[t];
  float4 o = make_float4(v.x*inv*wv.x, v.y*inv*wv.y, v.z*inv*wv.z, v.w*inv*wv.w);
  ((float4*)(out + (size_t)row * HID))[t] = o;
}

// ---------------- plain NT GEMM: C[M,N] = A[M,K]*B[N,K]^T (+res) ----------------
// M multiple of 128, N multiple of 64, K multiple of 16.
__global__ __launch_bounds__(256) void k_gemm_nt(const float* __restrict__ A,
                                                 const float* __restrict__ B,
                                                 const float* __restrict__ res,
                                                 float* __restrict__ C,
                                                 int M, int N, int Kd) {
  __shared__ __align__(16) float As[BKC][BM];
  __shared__ __align__(16) float Bs[BKC][BN];
  const int t = threadIdx.x;
  const int tx = t & 15, ty = t >> 4;
  const int m0 = blockIdx.y * BM, n0 = blockIdx.x * BN;
  const int arow = t >> 1, ak0 = (t & 1) * 8;      // thread loads A row arow, k-floats ak0..ak0+7
  const int brow = t >> 2, bk0 = (t & 3) * 4;      // thread loads B row brow, k-floats bk0..bk0+3
  const float* Ap = A + (size_t)(m0 + arow) * Kd + ak0;
  const float* Bp = B + (size_t)(n0 + brow) * Kd + bk0;
  float4 acc[8];
  #pragma unroll
  for (int i = 0; i < 8; ++i) acc[i] = make_float4(0.f, 0.f, 0.f, 0.f);
  for (int kk = 0; kk < Kd; kk += BKC) {
    float4 a0 = *(const float4*)(Ap + kk);
    float4 a1 = *(const float4*)(Ap + kk + 4);
    float4 b0 = *(const float4*)(Bp + kk);
    As[ak0+0][arow] = a0.x; As[ak0+1][arow] = a0.y; As[ak0+2][arow] = a0.z; As[ak0+3][arow] = a0.w;
    As[ak0+4][arow] = a1.x; As[ak0+5][arow] = a1.y; As[ak0+6][arow] = a1.z; As[ak0+7][arow] = a1.w;
    Bs[bk0+0][brow] = b0.x; Bs[bk0+1][brow] = b0.y; Bs[bk0+2][brow] = b0.z; Bs[bk0+3][brow] = b0.w;
    __syncthreads();
    #pragma unroll
    for (int k = 0; k < BKC; ++k) {
      float4 va0 = *(const float4*)&As[k][ty * 8];
      float4 va1 = *(const float4*)&As[k][ty * 8 + 4];
      float4 vb  = *(const float4*)&Bs[k][tx * 4];
      float av[8] = {va0.x, va0.y, va0.z, va0.w, va1.x, va1.y, va1.z, va1.w};
      #pragma unroll
      for (int i = 0; i < 8; ++i) {
        acc[i].x += av[i] * vb.x; acc[i].y += av[i] * vb.y;
        acc[i].z += av[i] * vb.z; acc[i].w += av[i] * vb.w;
      }
    }
    __syncthreads();
  }
  #pragma unroll
  for (int i = 0; i < 8; ++i) {
    const int r = m0 + ty * 8 + i, cidx = n0 + tx * 4;
    float4 o = acc[i];
    if (res) {
      float4 rv = *(const float4*)(res + (size_t)r * N + cidx);
      o.x += rv.x; o.y += rv.y; o.z += rv.z; o.w += rv.w;
    }
    *(float4*)(C + (size_t)r * N + cidx) = o;
  }
}

// ---------------- RoPE (in-place on q,k inside qkv) ----------------
__global__ __launch_bounds__(256) void k_rope(float* __restrict__ qkv) {
  const int s = blockIdx.x, t = threadIdx.x;
  float* rowp = qkv + (size_t)s * QKVW;
  const float LOG10000 = 9.210340371976184f;
  #pragma unroll
  for (int it = 0; it < 4; ++it) {
    const int idx = it * 256 + t;
    const int hh = idx >> 6, d = idx & 63;
    const int i = d & 31;
    const float ang = (float)s * expf(-(float)i * (1.0f / 32.0f) * LOG10000);
    float cv, sv;
    sincosf(ang, &sv, &cv);
    float* qp = rowp + hh * HDIM;
    float* kp = rowp + HID + hh * HDIM;
    const int pd = (d < 32) ? d + 32 : d - 32;
    const float q0 = qp[d], q1 = qp[pd];
    const float k0 = kp[d], k1 = kp[pd];
    const float rq = (d < 32) ? -q1 : q1;
    const float rk = (d < 32) ? -k1 : k1;
    __syncthreads();
    qp[d] = q0 * cv + rq * sv;
    kp[d] = k0 * cv + rk * sv;
  }
}

// ---------------- flash attention: 64-q tile, 32-k tile, online softmax ----------------
__global__ __launch_bounds__(256) void k_attn(const float* __restrict__ qkv,
                                              float* __restrict__ attn) {
  const int h  = blockIdx.x;
  const int qt = (int)gridDim.y - 1 - (int)blockIdx.y;  // heavy tiles first
  const int t  = threadIdx.x;
  const int qr = t >> 2, c = t & 3;
  const int qrow = qt * 64 + qr;

  __shared__ __align__(16) float ks[32][68];
  __shared__ __align__(16) float vs[32][68];
  __shared__ float sp[64][36];
  __shared__ float pm[64][4];
  __shared__ float psum_s[64][4];
  __shared__ float mS[64], lS[64], ccS[64];

  float qreg[64];
  {
    const float4* qp = (const float4*)(qkv + (size_t)qrow * QKVW + h * HDIM);
    #pragma unroll
    for (int i = 0; i < 16; ++i) {
      float4 v = qp[i];
      qreg[4*i+0] = v.x * 0.125f; qreg[4*i+1] = v.y * 0.125f;
      qreg[4*i+2] = v.z * 0.125f; qreg[4*i+3] = v.w * 0.125f;
    }
  }
  float oreg[16];
  #pragma unroll
  for (int i = 0; i < 16; ++i) oreg[i] = 0.f;
  if (c == 0) { mS[qr] = -INFINITY; lS[qr] = 0.f; }

  const int nkt = qt * 2 + 2;
  for (int kt = 0; kt < nkt; ++kt) {
    { // stage K/V tile: 32 keys x 64 dims; thread: row t>>3, 8 floats at (t&7)*8
      const int row = t >> 3;
      const int col0 = (t & 7) * 8;
      const float* base = qkv + (size_t)(kt * 32 + row) * QKVW + HID + h * HDIM + col0;
      float4 kv0 = *(const float4*)(base);
      float4 kv1 = *(const float4*)(base + 4);
      float4 vv0 = *(const float4*)(base + HID);
      float4 vv1 = *(const float4*)(base + HID + 4);
      ks[row][col0+0]=kv0.x; ks[row][col0+1]=kv0.y; ks[row][col0+2]=kv0.z; ks[row][col0+3]=kv0.w;
      ks[row][col0+4]=kv1.x; ks[row][col0+5]=kv1.y; ks[row][col0+6]=kv1.z; ks[row][col0+7]=kv1.w;
      vs[row][col0+0]=vv0.x; vs[row][col0+1]=vv0.y; vs[row][col0+2]=vv0.z; vs[row][col0+3]=vv0.w;
      vs[row][col0+4]=vv1.x; vs[row][col0+5]=vv1.y; vs[row][col0+6]=vv1.z; vs[row][col0+7]=vv1.w;
    }
    __syncthreads();
    // scores for keys j = c + 4*jj (stride-4 keeps LDS banks distinct per c)
    float svv[8]; float smax = -INFINITY;
    #pragma unroll
    for (int jj = 0; jj < 8; ++jj) {
      const int j = c + 4 * jj;
      float acc = 0.f;
      #pragma unroll
      for (int dd = 0; dd < 16; ++dd) {
        float4 kv = *(const float4*)&ks[j][dd * 4];
        acc += qreg[4*dd+0]*kv.x + qreg[4*dd+1]*kv.y + qreg[4*dd+2]*kv.z + qreg[4*dd+3]*kv.w;
      }
      if (kt * 32 + j > qrow) acc = -INFINITY;
      svv[jj] = acc;
      smax = fmaxf(smax, acc);
    }
    pm[qr][c] = smax;
    __syncthreads();
    if (c == 0) {
      const float mold = mS[qr];
      const float mnew = fmaxf(mold, fmaxf(fmaxf(pm[qr][0], pm[qr][1]), fmaxf(pm[qr][2], pm[qr][3])));
      mS[qr] = mnew;
      ccS[qr] = expf(mold - mnew);
    }
    __syncthreads();
    const float mnew = mS[qr];
    const float corr = ccS[qr];
    float psum = 0.f;
    #pragma unroll
    for (int jj = 0; jj < 8; ++jj) {
      const int j = c + 4 * jj;
      const float p = expf(svv[jj] - mnew);  // exp(-inf - m) = 0 for masked
      sp[qr][j] = p;
      psum += p;
    }
    psum_s[qr][c] = psum;
    #pragma unroll
    for (int i = 0; i < 16; ++i) oreg[i] *= corr;
    __syncthreads();
    if (c == 0)
      lS[qr] = lS[qr] * corr + psum_s[qr][0] + psum_s[qr][1] + psum_s[qr][2] + psum_s[qr][3];
    #pragma unroll
    for (int j = 0; j < 32; ++j) {
      const float p = sp[qr][j];
      const float4* vr = (const float4*)&vs[j][c * 16];
      float4 v0 = vr[0], v1 = vr[1], v2 = vr[2], v3 = vr[3];
      oreg[0]  += p*v0.x; oreg[1]  += p*v0.y; oreg[2]  += p*v0.z; oreg[3]  += p*v0.w;
      oreg[4]  += p*v1.x; oreg[5]  += p*v1.y; oreg[6]  += p*v1.z; oreg[7]  += p*v1.w;
      oreg[8]  += p*v2.x; oreg[9]  += p*v2.y; oreg[10] += p*v2.z; oreg[11] += p*v2.w;
      oreg[12] += p*v3.x; oreg[13] += p*v3.y; oreg[14] += p*v3.z; oreg[15] += p*v3.w;
    }
    __syncthreads();
  }
  const float inv = 1.0f / lS[qr];
  float* op = attn + (size_t)qrow * HID + h * HDIM + c * 16;
  #pragma unroll
  for (int i = 0; i < 4; ++i) {
    float4 o = make_float4(oreg[4*i+0]*inv, oreg[4*i+1]*inv, oreg[4*i+2]*inv, oreg[4*i+3]*inv);
    *(float4*)(op + 4 * i) = o;
  }
}

// ---------------- router: logits -> top-2 (gate = softmax over the two logits) ----------------
__global__ __launch_bounds__(64) void k_router(const float* __restrict__ xn2,
                                               const float* __restrict__ rw,
                                               int* __restrict__ tidx,
                                               float* __restrict__ tw) {
  const int n = blockIdx.x, lane = threadIdx.x;
  float lg[8] = {0.f,0.f,0.f,0.f,0.f,0.f,0.f,0.f};
  #pragma unroll
  for (int i = 0; i < 4; ++i) {
    float4 xv = ((const float4*)(xn2 + (size_t)n * HID))[lane + 64 * i];
    #pragma unroll
    for (int e = 0; e < 8; ++e) {
      float4 wv = ((const float4*)(rw + (size_t)e * HID))[lane + 64 * i];
      lg[e] += xv.x*wv.x + xv.y*wv.y + xv.z*wv.z + xv.w*wv.w;
    }
  }
  #pragma unroll
  for (int e = 0; e < 8; ++e) {
    #pragma unroll
    for (int off = 32; off; off >>= 1) lg[e] += __shfl_xor(lg[e], off);
  }
  if (lane == 0) {
    int e1 = 0; float l1 = lg[0];
    #pragma unroll
    for (int e = 1; e < 8; ++e) if (lg[e] > l1) { l1 = lg[e]; e1 = e; }
    int e2 = -1; float l2 = -INFINITY;
    #pragma unroll
    for (int e = 0; e < 8; ++e) if (e != e1 && lg[e] > l2) { l2 = lg[e]; e2 = e; }
    const float w1 = 1.0f / (1.0f + expf(l2 - l1));
    tidx[n * 2] = e1; tidx[n * 2 + 1] = e2;
    tw[n * 2] = w1;  tw[n * 2 + 1] = 1.0f - w1;
  }
}

// ---------------- capacity scan (exact token-order cumsum) + aux loss ----------------
__global__ __launch_bounds__(512) void k_scan(const int* __restrict__ tidx,
                                              int* __restrict__ slotk,
                                              int* __restrict__ perm,
                                              int* __restrict__ counts,
                                              float* __restrict__ aux_out) {
  const int t = threadIdx.x;
  const int e = t >> 6, lane = t & 63;
  __shared__ int cls[8];
  int offset = 0;
  for (int chunk = 0; chunk < SEQ / 64; ++chunk) {
    const int n = chunk * 64 + lane;
    const int i0 = tidx[n * 2], i1 = tidx[n * 2 + 1];
    const bool bit = (i0 == e) || (i1 == e);
    const unsigned long long mask = __ballot(bit);
    const int pos = offset + __popcll(mask & ((1ull << lane) - 1ull));
    if (bit) {
      const int kk = (i0 == e) ? 0 : 1;
      slotk[n * 2 + kk] = pos;
      if (pos < CAPE) perm[e * CAPE + pos] = n;
    }
    offset += __popcll(mask);
  }
  if (lane == 0) { counts[e] = offset; cls[e] = offset; }
  __syncthreads();
  if (t == 0) {
    float mean = 0.f;
    for (int i = 0; i < 8; ++i) mean += (float)cls[i];
    mean /= (8.0f * (float)SEQ);
    float var = 0.f;
    for (int i = 0; i < 8; ++i) {
      const float f = (float)cls[i] / (float)SEQ;
      var += (f - mean) * (f - mean);
    }
    var /= 7.0f;                       // ddof=1
    aux_out[0] = var * 8.0f;           // * E
  }
}

// ---------------- MoE gate/up GEMM with gathered rows + fused SiLU*u ----------------
__global__ __launch_bounds__(256) void k_gemm_gu(const float* __restrict__ X,
                                                 const float* __restrict__ Wg,
                                                 const float* __restrict__ Wu,
                                                 const int* __restrict__ perm,
                                                 const int* __restrict__ counts,
                                                 float* __restrict__ act) {
  const int e = blockIdx.z;
  const int rows = min(counts[e], CAPE);
  const int m0 = blockIdx.y * BM;
  if (m0 >= rows) return;
  const int n0 = blockIdx.x * BN;
  __shared__ __align__(16) float As[BKC][BM];
  __shared__ __align__(16) float Gs[BKC][BN];
  __shared__ __align__(16) float Us[BKC][BN];
  const int t = threadIdx.x;
  const int tx = t & 15, ty = t >> 4;
  const int arow = t >> 1, ak0 = (t & 1) * 8;
  const int brow = t >> 2, bk0 = (t & 3) * 4;
  const int r = m0 + arow;
  const float* Ap = nullptr;
  if (r < rows) Ap = X + (size_t)perm[e * CAPE + r] * HID + ak0;
  const float* Gp = Wg + (size_t)e * IDIM * HID + (size_t)(n0 + brow) * HID + bk0;
  const float* Up = Wu + (size_t)e * IDIM * HID + (size_t)(n0 + brow) * HID + bk0;
  float4 accg[8], accu[8];
  #pragma unroll
  for (int i = 0; i < 8; ++i) { accg[i] = make_float4(0.f,0.f,0.f,0.f); accu[i] = make_float4(0.f,0.f,0.f,0.f); }
  for (int kk = 0; kk < HID; kk += BKC) {
    float4 a0 = make_float4(0.f,0.f,0.f,0.f), a1 = make_float4(0.f,0.f,0.f,0.f);
    if (Ap) { a0 = *(const float4*)(Ap + kk); a1 = *(const float4*)(Ap + kk + 4); }
    float4 g0 = *(const float4*)(Gp + kk);
    float4 u0 = *(const float4*)(Up + kk);
    As[ak0+0][arow] = a0.x; As[ak0+1][arow] = a0.y; As[ak0+2][arow] = a0.z; As[ak0+3][arow] = a0.w;
    As[ak0+4][arow] = a1.x; As[ak0+5][arow] = a1.y; As[ak0+6][arow] = a1.z; As[ak0+7][arow] = a1.w;
    Gs[bk0+0][brow] = g0.x; Gs[bk0+1][brow] = g0.y; Gs[bk0+2][brow] = g0.z; Gs[bk0+3][brow] = g0.w;
    Us[bk0+0][brow] = u0.x; Us[bk0+1][brow] = u0.y; Us[bk0+2][brow] = u0.z; Us[bk0+3][brow] = u0.w;
    __syncthreads();
    #pragma unroll
    for (int k = 0; k < BKC; ++k) {
      float4 va0 = *(const float4*)&As[k][ty * 8];
      float4 va1 = *(const float4*)&As[k][ty * 8 + 4];
      float4 vg  = *(const float4*)&Gs[k][tx * 4];
      float4 vu  = *(const float4*)&Us[k][tx * 4];
      float av[8] = {va0.x, va0.y, va0.z, va0.w, va1.x, va1.y, va1.z, va1.w};
      #pragma unroll
      for (int i = 0; i < 8; ++i) {
        accg[i].x += av[i]*vg.x; accg[i].y += av[i]*vg.y; accg[i].z += av[i]*vg.z; accg[i].w += av[i]*vg.w;
        accu[i].x += av[i]*vu.x; accu[i].y += av[i]*vu.y; accu[i].z += av[i]*vu.z; accu[i].w += av[i]*vu.w;
      }
    }
    __syncthreads();
  }
  #pragma unroll
  for (int i = 0; i < 8; ++i) {
    const int rr = m0 + ty * 8 + i;
    if (rr < rows) {
      float4 g = accg[i], u = accu[i];
      float4 o;
      o.x = g.x / (1.f + expf(-g.x)) * u.x;
      o.y = g.y / (1.f + expf(-g.y)) * u.y;
      o.z = g.z / (1.f + expf(-g.z)) * u.z;
      o.w = g.w / (1.f + expf(-g.w)) * u.w;
      *(float4*)(act + ((size_t)e * CAPE + rr) * IDIM + n0 + tx * 4) = o;
    }
  }
}

// ---------------- MoE down GEMM ----------------
__global__ __launch_bounds__(256) void k_gemm_down(const float* __restrict__ act,
                                                   const float* __restrict__ Wd,
                                                   const int* __restrict__ counts,
                                                   float* __restrict__ y) {
  const int e = blockIdx.z;
  const int rows = min(counts[e], CAPE);
  const int m0 = blockIdx.y * BM;
  if (m0 >= rows) return;
  const int n0 = blockIdx.x * BN;
  __shared__ __align__(16) float As[BKC][BM];
  __shared__ __align__(16) float Bs[BKC][BN];
  const int t = threadIdx.x;
  const int tx = t & 15, ty = t >> 4;
  const int arow = t >> 1, ak0 = (t & 1) * 8;
  const int brow = t >> 2, bk0 = (t & 3) * 4;
  const int r = m0 + arow;
  const float* Ap = (r < rows) ? act + ((size_t)e * CAPE + r) * IDIM + ak0 : nullptr;
  const float* Bp = Wd + (size_t)e * HID * IDIM + (size_t)(n0 + brow) * IDIM + bk0;
  float4 acc[8];
  #pragma unroll
  for (int i = 0; i < 8; ++i) acc[i] = make_float4(0.f, 0.f, 0.f, 0.f);
  for (int kk = 0; kk < IDIM; kk += BKC) {
    float4 a0 = make_float4(0.f,0.f,0.f,0.f), a1 = make_float4(0.f,0.f,0.f,0.f);
    if (Ap) { a0 = *(const float4*)(Ap + kk); a1 = *(const float4*)(Ap + kk + 4); }
    float4 b0 = *(const float4*)(Bp + kk);
    As[ak0+0][arow] = a0.x; As[ak0+1][arow] = a0.y; As[ak0+2][arow] = a0.z; As[ak0+3][arow] = a0.w;
    As[ak0+4][arow] = a1.x; As[ak0+5][arow] = a1.y; As[ak0+6][arow] = a1.z; As[ak0+7][arow] = a1.w;
    Bs[bk0+0][brow] = b0.x; Bs[bk0+1][brow] = b0.y; Bs[bk0+2][brow] = b0.z; Bs[bk0+3][brow] = b0.w;
    __syncthreads();
    #pragma unroll
    for (int k = 0; k < BKC; ++k) {
      float4 va0 = *(const float4*)&As[k][ty * 8];
      float4 va1 = *(const float4*)&As[k][ty * 8 + 4];
      float4 vb  = *(const float4*)&Bs[k][tx * 4];
      float av[8] = {va0.x, va0.y, va0.z, va0.w, va1.x, va1.y, va1.z, va1.w};
      #pragma unroll
      for (int i = 0; i < 8; ++i) {
        acc[i].x += av[i]*vb.x; acc[i].y += av[i]*vb.y;
        acc[i].z += av[i]*vb.z; acc[i].w += av[i]*vb.w;
      }
    }
    __syncthreads();
  }
  #pragma unroll
  for (int i = 0; i < 8; ++i) {
    const int rr = m0 + ty * 8 + i;
    if (rr < rows)
      *(float4*)(y + ((size_t)e * CAPE + rr) * HID + n0 + tx * 4) = acc[i];
  }
}

// ---------------- combine: out = x1 + sum_k gate_k * y[e_k][slot_k] ----------------
__global__ __launch_bounds__(256) void k_combine(const float* __restrict__ x1,
                                                 const float* __restrict__ y,
                                                 const int* __restrict__ tidx,
                                                 const float* __restrict__ tw,
                                                 const int* __restrict__ slotk,
                                                 float* __restrict__ out) {
  const int n = blockIdx.x, t = threadIdx.x;
  float4 acc = ((const float4*)(x1 + (size_t)n * HID))[t];
  #pragma unroll
  for (int k = 0; k < 2; ++k) {
    const int slot = slotk[n * 2 + k];
    if (slot < CAPE) {
      const int e = tidx[n * 2 + k];
      const float w = tw[n * 2 + k];
      float4 v = ((const float4*)(y + ((size_t)e * CAPE + slot) * HID))[t];
      acc.x += w * v.x; acc.y += w * v.y; acc.z += w * v.z; acc.w += w * v.w;
    }
  }
  ((float4*)(out + (size_t)n * HID))[t] = acc;
}

extern "C" void kernel_launch(void* const* d_in, const int* in_sizes, int n_in,
                              void* d_out, int out_size, void* d_ws, size_t ws_size,
                              hipStream_t stream) {
  const float* x     = (const float*)d_in[0];
  const float* anw   = (const float*)d_in[1];
  const float* qkv_w = (const float*)d_in[2];
  const float* o_w   = (const float*)d_in[3];
  const float* fnw   = (const float*)d_in[4];
  const float* rw    = (const float*)d_in[5];
  const float* wg    = (const float*)d_in[6];
  const float* wu    = (const float*)d_in[7];
  const float* wd    = (const float*)d_in[8];
  (void)in_sizes; (void)n_in; (void)out_size; (void)ws_size;
  float* out = (float*)d_out;

  float* ws = (float*)d_ws;
  size_t off = 0;
  float* xn   = ws + off; off += (size_t)SEQ * HID;
  float* qkv  = ws + off; off += (size_t)SEQ * QKVW;
  float* attn = ws + off; off += (size_t)SEQ * HID;
  float* x1   = ws + off; off += (size_t)SEQ * HID;
  float* xn2  = ws + off; off += (size_t)SEQ * HID;
  float* ybuf = ws + off; off += (size_t)NEXP * CAPE * HID;
  float* act  = ws + off; off += (size_t)NEXP * CAPE * IDIM;
  float* tw   = ws + off; off += SEQ * 2;
  int* tidx   = (int*)(ws + off); off += SEQ * 2;
  int* slotk  = (int*)(ws + off); off += SEQ * 2;
  int* perm   = (int*)(ws + off); off += NEXP * CAPE;
  int* counts = (int*)(ws + off); off += 8;

  k_rmsnorm<<<SEQ, 256, 0, stream>>>(x, anw, xn);
  k_gemm_nt<<<dim3(QKVW / BN, SEQ / BM), 256, 0, stream>>>(xn, qkv_w, nullptr, qkv, SEQ, QKVW, HID);
  k_rope<<<SEQ, 256, 0, stream>>>(qkv);
  k_attn<<<dim3(NHEAD, SEQ / 64), 256, 0, stream>>>(qkv, attn);
  k_gemm_nt<<<dim3(HID / BN, SEQ / BM), 256, 0, stream>>>(attn, o_w, x, x1, SEQ, HID, HID);
  k_rmsnorm<<<SEQ, 256, 0, stream>>>(x1, fnw, xn2);
  k_router<<<SEQ, 64, 0, stream>>>(xn2, rw, tidx, tw);
  k_scan<<<1, 512, 0, stream>>>(tidx, slotk, perm, counts, out + (size_t)SEQ * HID);
  k_gemm_gu<<<dim3(IDIM / BN, CAPE / BM, NEXP), 256, 0, stream>>>(xn2, wg, wu, perm, counts, act);
  k_gemm_down<<<dim3(HID / BN, CAPE / BM, NEXP), 256, 0, stream>>>(act, wd, counts, ybuf);
  k_combine<<<SEQ, 256, 0, stream>>>(x1, ybuf, tidx, tw, slotk, out);
}

// Round 2
// 1234.239 us; speedup vs baseline: 2.0279x; 2.0279x over previous
//
#include <hip/hip_runtime.h>
#include <math.h>

#define SEQ   2048
#define HID   1024
#define NHEAD 16
#define HDIM  64
#define NEXP  8
#define IDIM  4096
#define CAPE  1024
#define QKVW  3072

#define BM 128
#define BN 64
#define BKC 16

typedef __bf16 bf16x8 __attribute__((ext_vector_type(8)));
typedef __bf16 bf16x4 __attribute__((ext_vector_type(4)));
typedef float  f32x4  __attribute__((ext_vector_type(4)));

__device__ __forceinline__ void gld16(const void* g, void* l) {
  __builtin_amdgcn_global_load_lds((const __attribute__((address_space(1))) void*)g,
                                   (__attribute__((address_space(3))) void*)l, 16, 0, 0);
}

// ---------------- RMSNorm (optionally also emits bf16 copy) ----------------
__global__ __launch_bounds__(256) void k_rmsnorm(const float* __restrict__ x,
                                                 const float* __restrict__ w,
                                                 float* __restrict__ out,
                                                 __bf16* __restrict__ out_bf) {
  const int row = blockIdx.x, t = threadIdx.x;
  float4 v = ((const float4*)(x + (size_t)row * HID))[t];
  float ss = v.x*v.x + v.y*v.y + v.z*v.z + v.w*v.w;
  #pragma unroll
  for (int off = 32; off; off >>= 1) ss += __shfl_down(ss, off);
  __shared__ float red[4];
  if ((t & 63) == 0) red[t >> 6] = ss;
  __syncthreads();
  const float inv = rsqrtf((red[0] + red[1] + red[2] + red[3]) * (1.0f / HID) + 1e-6f);
  float4 wv = ((const float4*)w)[t];
  float4 o = make_float4(v.x*inv*wv.x, v.y*inv*wv.y, v.z*inv*wv.z, v.w*inv*wv.w);
  ((float4*)(out + (size_t)row * HID))[t] = o;
  if (out_bf) {
    bf16x4 ob; ob[0] = (__bf16)o.x; ob[1] = (__bf16)o.y; ob[2] = (__bf16)o.z; ob[3] = (__bf16)o.w;
    *(bf16x4*)(out_bf + (size_t)row * HID + t * 4) = ob;
  }
}

// ---------------- fp32 -> bf16 convert (8 elems/thread) ----------------
__global__ __launch_bounds__(256) void k_cvt_bf16(const float* __restrict__ in,
                                                  __bf16* __restrict__ out,
                                                  long n8) {
  const long i = ((long)blockIdx.x * 256 + threadIdx.x);
  if (i >= n8) return;
  const float4 a = *(const float4*)(in + i * 8);
  const float4 b = *(const float4*)(in + i * 8 + 4);
  bf16x8 o;
  o[0] = (__bf16)a.x; o[1] = (__bf16)a.y; o[2] = (__bf16)a.z; o[3] = (__bf16)a.w;
  o[4] = (__bf16)b.x; o[5] = (__bf16)b.y; o[6] = (__bf16)b.z; o[7] = (__bf16)b.w;
  *(bf16x8*)(out + i * 8) = o;
}

// ---------------- plain fp32 NT GEMM (attention path; router-accurate) ----------------
__global__ __launch_bounds__(256) void k_gemm_nt(const float* __restrict__ A,
                                                 const float* __restrict__ B,
                                                 const float* __restrict__ res,
                                                 float* __restrict__ C,
                                                 int M, int N, int Kd) {
  __shared__ __align__(16) float As[BKC][BM];
  __shared__ __align__(16) float Bs[BKC][BN];
  const int t = threadIdx.x;
  const int tx = t & 15, ty = t >> 4;
  const int m0 = blockIdx.y * BM, n0 = blockIdx.x * BN;
  const int arow = t >> 1, ak0 = (t & 1) * 8;
  const int brow = t >> 2, bk0 = (t & 3) * 4;
  const float* Ap = A + (size_t)(m0 + arow) * Kd + ak0;
  const float* Bp = B + (size_t)(n0 + brow) * Kd + bk0;
  float4 acc[8];
  #pragma unroll
  for (int i = 0; i < 8; ++i) acc[i] = make_float4(0.f, 0.f, 0.f, 0.f);
  for (int kk = 0; kk < Kd; kk += BKC) {
    float4 a0 = *(const float4*)(Ap + kk);
    float4 a1 = *(const float4*)(Ap + kk + 4);
    float4 b0 = *(const float4*)(Bp + kk);
    As[ak0+0][arow] = a0.x; As[ak0+1][arow] = a0.y; As[ak0+2][arow] = a0.z; As[ak0+3][arow] = a0.w;
    As[ak0+4][arow] = a1.x; As[ak0+5][arow] = a1.y; As[ak0+6][arow] = a1.z; As[ak0+7][arow] = a1.w;
    Bs[bk0+0][brow] = b0.x; Bs[bk0+1][brow] = b0.y; Bs[bk0+2][brow] = b0.z; Bs[bk0+3][brow] = b0.w;
    __syncthreads();
    #pragma unroll
    for (int k = 0; k < BKC; ++k) {
      float4 va0 = *(const float4*)&As[k][ty * 8];
      float4 va1 = *(const float4*)&As[k][ty * 8 + 4];
      float4 vb  = *(const float4*)&Bs[k][tx * 4];
      float av[8] = {va0.x, va0.y, va0.z, va0.w, va1.x, va1.y, va1.z, va1.w};
      #pragma unroll
      for (int i = 0; i < 8; ++i) {
        acc[i].x += av[i] * vb.x; acc[i].y += av[i] * vb.y;
        acc[i].z += av[i] * vb.z; acc[i].w += av[i] * vb.w;
      }
    }
    __syncthreads();
  }
  #pragma unroll
  for (int i = 0; i < 8; ++i) {
    const int r = m0 + ty * 8 + i, cidx = n0 + tx * 4;
    float4 o = acc[i];
    if (res) {
      float4 rv = *(const float4*)(res + (size_t)r * N + cidx);
      o.x += rv.x; o.y += rv.y; o.z += rv.z; o.w += rv.w;
    }
    *(float4*)(C + (size_t)r * N + cidx) = o;
  }
}

// ---------------- RoPE (in-place on q,k inside qkv) ----------------
__global__ __launch_bounds__(256) void k_rope(float* __restrict__ qkv) {
  const int s = blockIdx.x, t = threadIdx.x;
  float* rowp = qkv + (size_t)s * QKVW;
  const float LOG10000 = 9.210340371976184f;
  #pragma unroll
  for (int it = 0; it < 4; ++it) {
    const int idx = it * 256 + t;
    const int hh = idx >> 6, d = idx & 63;
    const int i = d & 31;
    const float ang = (float)s * expf(-(float)i * (1.0f / 32.0f) * LOG10000);
    float cv, sv;
    sincosf(ang, &sv, &cv);
    float* qp = rowp + hh * HDIM;
    float* kp = rowp + HID + hh * HDIM;
    const int pd = (d < 32) ? d + 32 : d - 32;
    const float q0 = qp[d], q1 = qp[pd];
    const float k0 = kp[d], k1 = kp[pd];
    const float rq = (d < 32) ? -q1 : q1;
    const float rk = (d < 32) ? -k1 : k1;
    __syncthreads();
    qp[d] = q0 * cv + rq * sv;
    kp[d] = k0 * cv + rk * sv;
  }
}

// ---------------- flash attention fp32 ----------------
__global__ __launch_bounds__(256) void k_attn(const float* __restrict__ qkv,
                                              float* __restrict__ attn) {
  const int h  = blockIdx.x;
  const int qt = (int)gridDim.y - 1 - (int)blockIdx.y;
  const int t  = threadIdx.x;
  const int qr = t >> 2, c = t & 3;
  const int qrow = qt * 64 + qr;

  __shared__ __align__(16) float ks[32][68];
  __shared__ __align__(16) float vs[32][68];
  __shared__ float sp[64][36];
  __shared__ float pm[64][4];
  __shared__ float psum_s[64][4];
  __shared__ float mS[64], lS[64], ccS[64];

  float qreg[64];
  {
    const float4* qp = (const float4*)(qkv + (size_t)qrow * QKVW + h * HDIM);
    #pragma unroll
    for (int i = 0; i < 16; ++i) {
      float4 v = qp[i];
      qreg[4*i+0] = v.x * 0.125f; qreg[4*i+1] = v.y * 0.125f;
      qreg[4*i+2] = v.z * 0.125f; qreg[4*i+3] = v.w * 0.125f;
    }
  }
  float oreg[16];
  #pragma unroll
  for (int i = 0; i < 16; ++i) oreg[i] = 0.f;
  if (c == 0) { mS[qr] = -INFINITY; lS[qr] = 0.f; }

  const int nkt = qt * 2 + 2;
  for (int kt = 0; kt < nkt; ++kt) {
    {
      const int row = t >> 3;
      const int col0 = (t & 7) * 8;
      const float* base = qkv + (size_t)(kt * 32 + row) * QKVW + HID + h * HDIM + col0;
      float4 kv0 = *(const float4*)(base);
      float4 kv1 = *(const float4*)(base + 4);
      float4 vv0 = *(const float4*)(base + HID);
      float4 vv1 = *(const float4*)(base + HID + 4);
      ks[row][col0+0]=kv0.x; ks[row][col0+1]=kv0.y; ks[row][col0+2]=kv0.z; ks[row][col0+3]=kv0.w;
      ks[row][col0+4]=kv1.x; ks[row][col0+5]=kv1.y; ks[row][col0+6]=kv1.z; ks[row][col0+7]=kv1.w;
      vs[row][col0+0]=vv0.x; vs[row][col0+1]=vv0.y; vs[row][col0+2]=vv0.z; vs[row][col0+3]=vv0.w;
      vs[row][col0+4]=vv1.x; vs[row][col0+5]=vv1.y; vs[row][col0+6]=vv1.z; vs[row][col0+7]=vv1.w;
    }
    __syncthreads();
    float svv[8]; float smax = -INFINITY;
    #pragma unroll
    for (int jj = 0; jj < 8; ++jj) {
      const int j = c + 4 * jj;
      float acc = 0.f;
      #pragma unroll
      for (int dd = 0; dd < 16; ++dd) {
        float4 kv = *(const float4*)&ks[j][dd * 4];
        acc += qreg[4*dd+0]*kv.x + qreg[4*dd+1]*kv.y + qreg[4*dd+2]*kv.z + qreg[4*dd+3]*kv.w;
      }
      if (kt * 32 + j > qrow) acc = -INFINITY;
      svv[jj] = acc;
      smax = fmaxf(smax, acc);
    }
    pm[qr][c] = smax;
    __syncthreads();
    if (c == 0) {
      const float mold = mS[qr];
      const float mnew = fmaxf(mold, fmaxf(fmaxf(pm[qr][0], pm[qr][1]), fmaxf(pm[qr][2], pm[qr][3])));
      mS[qr] = mnew;
      ccS[qr] = expf(mold - mnew);
    }
    __syncthreads();
    const float mnew = mS[qr];
    const float corr = ccS[qr];
    float psum = 0.f;
    #pragma unroll
    for (int jj = 0; jj < 8; ++jj) {
      const int j = c + 4 * jj;
      const float p = expf(svv[jj] - mnew);
      sp[qr][j] = p;
      psum += p;
    }
    psum_s[qr][c] = psum;
    #pragma unroll
    for (int i = 0; i < 16; ++i) oreg[i] *= corr;
    __syncthreads();
    if (c == 0)
      lS[qr] = lS[qr] * corr + psum_s[qr][0] + psum_s[qr][1] + psum_s[qr][2] + psum_s[qr][3];
    #pragma unroll
    for (int j = 0; j < 32; ++j) {
      const float p = sp[qr][j];
      const float4* vr = (const float4*)&vs[j][c * 16];
      float4 v0 = vr[0], v1 = vr[1], v2 = vr[2], v3 = vr[3];
      oreg[0]  += p*v0.x; oreg[1]  += p*v0.y; oreg[2]  += p*v0.z; oreg[3]  += p*v0.w;
      oreg[4]  += p*v1.x; oreg[5]  += p*v1.y; oreg[6]  += p*v1.z; oreg[7]  += p*v1.w;
      oreg[8]  += p*v2.x; oreg[9]  += p*v2.y; oreg[10] += p*v2.z; oreg[11] += p*v2.w;
      oreg[12] += p*v3.x; oreg[13] += p*v3.y; oreg[14] += p*v3.z; oreg[15] += p*v3.w;
    }
    __syncthreads();
  }
  const float inv = 1.0f / lS[qr];
  float* op = attn + (size_t)qrow * HID + h * HDIM + c * 16;
  #pragma unroll
  for (int i = 0; i < 4; ++i) {
    float4 o = make_float4(oreg[4*i+0]*inv, oreg[4*i+1]*inv, oreg[4*i+2]*inv, oreg[4*i+3]*inv);
    *(float4*)(op + 4 * i) = o;
  }
}

// ---------------- router (fp32, must match reference's discrete top-2) ----------------
__global__ __launch_bounds__(64) void k_router(const float* __restrict__ xn2,
                                               const float* __restrict__ rw,
                                               int* __restrict__ tidx,
                                               float* __restrict__ tw) {
  const int n = blockIdx.x, lane = threadIdx.x;
  float lg[8] = {0.f,0.f,0.f,0.f,0.f,0.f,0.f,0.f};
  #pragma unroll
  for (int i = 0; i < 4; ++i) {
    float4 xv = ((const float4*)(xn2 + (size_t)n * HID))[lane + 64 * i];
    #pragma unroll
    for (int e = 0; e < 8; ++e) {
      float4 wv = ((const float4*)(rw + (size_t)e * HID))[lane + 64 * i];
      lg[e] += xv.x*wv.x + xv.y*wv.y + xv.z*wv.z + xv.w*wv.w;
    }
  }
  #pragma unroll
  for (int e = 0; e < 8; ++e) {
    #pragma unroll
    for (int off = 32; off; off >>= 1) lg[e] += __shfl_xor(lg[e], off);
  }
  if (lane == 0) {
    int e1 = 0; float l1 = lg[0];
    #pragma unroll
    for (int e = 1; e < 8; ++e) if (lg[e] > l1) { l1 = lg[e]; e1 = e; }
    int e2 = -1; float l2 = -INFINITY;
    #pragma unroll
    for (int e = 0; e < 8; ++e) if (e != e1 && lg[e] > l2) { l2 = lg[e]; e2 = e; }
    const float w1 = 1.0f / (1.0f + expf(l2 - l1));
    tidx[n * 2] = e1; tidx[n * 2 + 1] = e2;
    tw[n * 2] = w1;  tw[n * 2 + 1] = 1.0f - w1;
  }
}

// ---------------- capacity scan + aux loss ----------------
__global__ __launch_bounds__(512) void k_scan(const int* __restrict__ tidx,
                                              int* __restrict__ slotk,
                                              int* __restrict__ perm,
                                              int* __restrict__ counts,
                                              float* __restrict__ aux_out) {
  const int t = threadIdx.x;
  const int e = t >> 6, lane = t & 63;
  __shared__ int cls[8];
  int offset = 0;
  for (int chunk = 0; chunk < SEQ / 64; ++chunk) {
    const int n = chunk * 64 + lane;
    const int i0 = tidx[n * 2], i1 = tidx[n * 2 + 1];
    const bool bit = (i0 == e) || (i1 == e);
    const unsigned long long mask = __ballot(bit);
    const int pos = offset + __popcll(mask & ((1ull << lane) - 1ull));
    if (bit) {
      const int kk = (i0 == e) ? 0 : 1;
      slotk[n * 2 + kk] = pos;
      if (pos < CAPE) perm[e * CAPE + pos] = n;
    }
    offset += __popcll(mask);
  }
  if (lane == 0) { counts[e] = offset; cls[e] = offset; }
  __syncthreads();
  if (t == 0) {
    float mean = 0.f;
    for (int i = 0; i < 8; ++i) mean += (float)cls[i];
    mean /= (8.0f * (float)SEQ);
    float var = 0.f;
    for (int i = 0; i < 8; ++i) {
      const float f = (float)cls[i] / (float)SEQ;
      var += (f - mean) * (f - mean);
    }
    var /= 7.0f;
    aux_out[0] = var * 8.0f;
  }
}

// ---------------- MoE gate/up: bf16 MFMA, gathered A, fused SiLU*u -> bf16 act ----------------
// 128x128 tile, BK=32, 4 waves, each wave 64x64 (4x4 MFMA 16x16x32), global_load_lds width 16.
__global__ __launch_bounds__(256, 2) void k_moe_gu(const __bf16* __restrict__ X,
                                                   const __bf16* __restrict__ Wg,
                                                   const __bf16* __restrict__ Wu,
                                                   const int* __restrict__ perm,
                                                   const int* __restrict__ counts,
                                                   __bf16* __restrict__ act) {
  const int e = blockIdx.z;
  const int rows = min(counts[e], CAPE);
  const int m0 = blockIdx.y * 128;
  if (m0 >= rows) return;
  const int n0 = blockIdx.x * 128;
  __shared__ __align__(16) __bf16 As[128 * 32];
  __shared__ __align__(16) __bf16 Bgs[128 * 32];
  __shared__ __align__(16) __bf16 Bus[128 * 32];
  const int t = threadIdx.x;
  const int lane = t & 63, w = t >> 6;
  const int wr = w & 1, wc = w >> 1;
  const int sr = t >> 2;            // staging row within 64-row half
  const int sk = (t & 3) * 8;       // staging k element offset
  const int gr0 = m0 + sr, gr1 = m0 + 64 + sr;
  const size_t arow0 = (size_t)((gr0 < rows) ? perm[e * CAPE + gr0] : 0) * HID;
  const size_t arow1 = (size_t)((gr1 < rows) ? perm[e * CAPE + gr1] : 0) * HID;
  const __bf16* gB = Wg + (size_t)e * IDIM * HID;
  const __bf16* uB = Wu + (size_t)e * IDIM * HID;
  const size_t brow0 = (size_t)(n0 + sr) * HID, brow1 = (size_t)(n0 + 64 + sr) * HID;
  f32x4 accg[4][4], accu[4][4];
  #pragma unroll
  for (int i = 0; i < 4; ++i)
    #pragma unroll
    for (int j = 0; j < 4; ++j) { accg[i][j] = (f32x4)(0.f); accu[i][j] = (f32x4)(0.f); }

  for (int kk = 0; kk < HID; kk += 32) {
    gld16(X + arow0 + kk + sk, As + w * 512);
    gld16(X + arow1 + kk + sk, As + 2048 + w * 512);
    gld16(gB + brow0 + kk + sk, Bgs + w * 512);
    gld16(gB + brow1 + kk + sk, Bgs + 2048 + w * 512);
    gld16(uB + brow0 + kk + sk, Bus + w * 512);
    gld16(uB + brow1 + kk + sk, Bus + 2048 + w * 512);
    __syncthreads();
    bf16x8 a[4], bg[4], bu[4];
    #pragma unroll
    for (int i = 0; i < 4; ++i) {
      const int fo = (lane & 15) * 32 + (lane >> 4) * 8;
      a[i]  = *(const bf16x8*)&As[(wr * 64 + i * 16) * 32 + fo];
      bg[i] = *(const bf16x8*)&Bgs[(wc * 64 + i * 16) * 32 + fo];
      bu[i] = *(const bf16x8*)&Bus[(wc * 64 + i * 16) * 32 + fo];
    }
    #pragma unroll
    for (int i = 0; i < 4; ++i)
      #pragma unroll
      for (int j = 0; j < 4; ++j) {
        accg[i][j] = __builtin_amdgcn_mfma_f32_16x16x32_bf16(a[i], bg[j], accg[i][j], 0, 0, 0);
        accu[i][j] = __builtin_amdgcn_mfma_f32_16x16x32_bf16(a[i], bu[j], accu[i][j], 0, 0, 0);
      }
    __syncthreads();
  }
  const int cb = lane & 15, rb = (lane >> 4) * 4;
  #pragma unroll
  for (int i = 0; i < 4; ++i)
    #pragma unroll
    for (int r = 0; r < 4; ++r) {
      const int rr = m0 + wr * 64 + i * 16 + rb + r;
      if (rr < rows) {
        #pragma unroll
        for (int j = 0; j < 4; ++j) {
          const float g = accg[i][j][r], u = accu[i][j][r];
          const float v = g / (1.f + expf(-g)) * u;
          act[((size_t)e * CAPE + rr) * IDIM + n0 + wc * 64 + j * 16 + cb] = (__bf16)v;
        }
      }
    }
}

// ---------------- MoE down: bf16 MFMA ----------------
__global__ __launch_bounds__(256, 2) void k_moe_down(const __bf16* __restrict__ act,
                                                     const __bf16* __restrict__ Wd,
                                                     const int* __restrict__ counts,
                                                     float* __restrict__ y) {
  const int e = blockIdx.z;
  const int rows = min(counts[e], CAPE);
  const int m0 = blockIdx.y * 128;
  if (m0 >= rows) return;
  const int n0 = blockIdx.x * 128;
  __shared__ __align__(16) __bf16 As[128 * 32];
  __shared__ __align__(16) __bf16 Bs[128 * 32];
  const int t = threadIdx.x;
  const int lane = t & 63, w = t >> 6;
  const int wr = w & 1, wc = w >> 1;
  const int sr = t >> 2;
  const int sk = (t & 3) * 8;
  const __bf16* Ab = act + ((size_t)e * CAPE) * IDIM;
  const __bf16* Bb = Wd + (size_t)e * HID * IDIM;
  const size_t arow0 = (size_t)(m0 + sr) * IDIM, arow1 = (size_t)(m0 + 64 + sr) * IDIM;
  const size_t brow0 = (size_t)(n0 + sr) * IDIM, brow1 = (size_t)(n0 + 64 + sr) * IDIM;
  f32x4 acc[4][4];
  #pragma unroll
  for (int i = 0; i < 4; ++i)
    #pragma unroll
    for (int j = 0; j < 4; ++j) acc[i][j] = (f32x4)(0.f);

  for (int kk = 0; kk < IDIM; kk += 32) {
    gld16(Ab + arow0 + kk + sk, As + w * 512);
    gld16(Ab + arow1 + kk + sk, As + 2048 + w * 512);
    gld16(Bb + brow0 + kk + sk, Bs + w * 512);
    gld16(Bb + brow1 + kk + sk, Bs + 2048 + w * 512);
    __syncthreads();
    bf16x8 a[4], b[4];
    #pragma unroll
    for (int i = 0; i < 4; ++i) {
      const int fo = (lane & 15) * 32 + (lane >> 4) * 8;
      a[i] = *(const bf16x8*)&As[(wr * 64 + i * 16) * 32 + fo];
      b[i] = *(const bf16x8*)&Bs[(wc * 64 + i * 16) * 32 + fo];
    }
    #pragma unroll
    for (int i = 0; i < 4; ++i)
      #pragma unroll
      for (int j = 0; j < 4; ++j)
        acc[i][j] = __builtin_amdgcn_mfma_f32_16x16x32_bf16(a[i], b[j], acc[i][j], 0, 0, 0);
    __syncthreads();
  }
  const int cb = lane & 15, rb = (lane >> 4) * 4;
  #pragma unroll
  for (int i = 0; i < 4; ++i)
    #pragma unroll
    for (int r = 0; r < 4; ++r) {
      const int rr = m0 + wr * 64 + i * 16 + rb + r;
      if (rr < rows) {
        #pragma unroll
        for (int j = 0; j < 4; ++j)
          y[((size_t)e * CAPE + rr) * HID + n0 + wc * 64 + j * 16 + cb] = acc[i][j][r];
      }
    }
}

// ---------------- combine ----------------
__global__ __launch_bounds__(256) void k_combine(const float* __restrict__ x1,
                                                 const float* __restrict__ y,
                                                 const int* __restrict__ tidx,
                                                 const float* __restrict__ tw,
                                                 const int* __restrict__ slotk,
                                                 float* __restrict__ out) {
  const int n = blockIdx.x, t = threadIdx.x;
  float4 acc = ((const float4*)(x1 + (size_t)n * HID))[t];
  #pragma unroll
  for (int k = 0; k < 2; ++k) {
    const int slot = slotk[n * 2 + k];
    if (slot < CAPE) {
      const int e = tidx[n * 2 + k];
      const float w = tw[n * 2 + k];
      float4 v = ((const float4*)(y + ((size_t)e * CAPE + slot) * HID))[t];
      acc.x += w * v.x; acc.y += w * v.y; acc.z += w * v.z; acc.w += w * v.w;
    }
  }
  ((float4*)(out + (size_t)n * HID))[t] = acc;
}

extern "C" void kernel_launch(void* const* d_in, const int* in_sizes, int n_in,
                              void* d_out, int out_size, void* d_ws, size_t ws_size,
                              hipStream_t stream) {
  const float* x     = (const float*)d_in[0];
  const float* anw   = (const float*)d_in[1];
  const float* qkv_w = (const float*)d_in[2];
  const float* o_w   = (const float*)d_in[3];
  const float* fnw   = (const float*)d_in[4];
  const float* rw    = (const float*)d_in[5];
  const float* wg    = (const float*)d_in[6];
  const float* wu    = (const float*)d_in[7];
  const float* wd    = (const float*)d_in[8];
  (void)in_sizes; (void)n_in; (void)out_size; (void)ws_size;
  float* out = (float*)d_out;

  float* ws = (float*)d_ws;
  size_t off = 0;
  float* xn   = ws + off; off += (size_t)SEQ * HID;          // 2M
  float* qkv  = ws + off; off += (size_t)SEQ * QKVW;         // 6.29M
  float* attn = ws + off; off += (size_t)SEQ * HID;
  float* x1   = ws + off; off += (size_t)SEQ * HID;
  float* xn2  = ws + off; off += (size_t)SEQ * HID;
  float* ybuf = ws + off; off += (size_t)NEXP * CAPE * HID;  // 8.39M
  float* tw   = ws + off; off += SEQ * 2;
  int* tidx   = (int*)(ws + off); off += SEQ * 2;
  int* slotk  = (int*)(ws + off); off += SEQ * 2;
  int* perm   = (int*)(ws + off); off += NEXP * CAPE;
  int* counts = (int*)(ws + off); off += 16;
  // bf16 region (element counts; 2 bytes each)
  __bf16* bfbase = (__bf16*)(ws + off);
  size_t boff = 0;
  __bf16* xn2_bf = bfbase + boff; boff += (size_t)SEQ * HID;
  __bf16* wg_bf  = bfbase + boff; boff += (size_t)NEXP * IDIM * HID;
  __bf16* wu_bf  = bfbase + boff; boff += (size_t)NEXP * IDIM * HID;
  __bf16* wd_bf  = bfbase + boff; boff += (size_t)NEXP * HID * IDIM;
  __bf16* act_bf = bfbase + boff; boff += (size_t)NEXP * CAPE * IDIM;

  const long nw8 = (long)NEXP * IDIM * HID / 8;  // 4.19M chunks per weight tensor
  const int cvtGrid = (int)((nw8 + 255) / 256);
  k_cvt_bf16<<<cvtGrid, 256, 0, stream>>>(wg, wg_bf, nw8);
  k_cvt_bf16<<<cvtGrid, 256, 0, stream>>>(wu, wu_bf, nw8);
  k_cvt_bf16<<<cvtGrid, 256, 0, stream>>>(wd, wd_bf, nw8);

  k_rmsnorm<<<SEQ, 256, 0, stream>>>(x, anw, xn, (__bf16*)nullptr);
  k_gemm_nt<<<dim3(QKVW / BN, SEQ / BM), 256, 0, stream>>>(xn, qkv_w, nullptr, qkv, SEQ, QKVW, HID);
  k_rope<<<SEQ, 256, 0, stream>>>(qkv);
  k_attn<<<dim3(NHEAD, SEQ / 64), 256, 0, stream>>>(qkv, attn);
  k_gemm_nt<<<dim3(HID / BN, SEQ / BM), 256, 0, stream>>>(attn, o_w, x, x1, SEQ, HID, HID);
  k_rmsnorm<<<SEQ, 256, 0, stream>>>(x1, fnw, xn2, xn2_bf);
  k_router<<<SEQ, 64, 0, stream>>>(xn2, rw, tidx, tw);
  k_scan<<<1, 512, 0, stream>>>(tidx, slotk, perm, counts, out + (size_t)SEQ * HID);
  k_moe_gu<<<dim3(IDIM / 128, CAPE / 128, NEXP), 256, 0, stream>>>(xn2_bf, wg_bf, wu_bf, perm, counts, act_bf);
  k_moe_down<<<dim3(HID / 128, CAPE / 128, NEXP), 256, 0, stream>>>(act_bf, wd_bf, counts, ybuf);
  k_combine<<<SEQ, 256, 0, stream>>>(x1, ybuf, tidx, tw, slotk, out);
}

// Round 3
// 1109.216 us; speedup vs baseline: 2.2564x; 1.1127x over previous
//
#include <hip/hip_runtime.h>
#include <math.h>

#define SEQ   2048
#define HID   1024
#define NHEAD 16
#define HDIM  64
#define NEXP  8
#define IDIM  4096
#define CAPE  1024
#define QKVW  3072

typedef __bf16    bf16x8 __attribute__((ext_vector_type(8)));
typedef __bf16    bf16x4 __attribute__((ext_vector_type(4)));
typedef _Float16  f16x8  __attribute__((ext_vector_type(8)));
typedef _Float16  f16x4  __attribute__((ext_vector_type(4)));
typedef float     f32x4  __attribute__((ext_vector_type(4)));

__device__ __forceinline__ void gld16(const void* g, void* l) {
  __builtin_amdgcn_global_load_lds((const __attribute__((address_space(1))) void*)g,
                                   (__attribute__((address_space(3))) void*)l, 16, 0, 0);
}

// ---------------- RMSNorm: fp32 out (opt), bf16 out (opt), f16 hi/lo out (opt) ----------------
__global__ __launch_bounds__(256) void k_rmsnorm(const float* __restrict__ x,
                                                 const float* __restrict__ w,
                                                 float* __restrict__ out,
                                                 __bf16* __restrict__ out_bf,
                                                 _Float16* __restrict__ out_h,
                                                 _Float16* __restrict__ out_l) {
  const int row = blockIdx.x, t = threadIdx.x;
  float4 v = ((const float4*)(x + (size_t)row * HID))[t];
  float ss = v.x*v.x + v.y*v.y + v.z*v.z + v.w*v.w;
  #pragma unroll
  for (int off = 32; off; off >>= 1) ss += __shfl_down(ss, off);
  __shared__ float red[4];
  if ((t & 63) == 0) red[t >> 6] = ss;
  __syncthreads();
  const float inv = rsqrtf((red[0] + red[1] + red[2] + red[3]) * (1.0f / HID) + 1e-6f);
  float4 wv = ((const float4*)w)[t];
  float4 o = make_float4(v.x*inv*wv.x, v.y*inv*wv.y, v.z*inv*wv.z, v.w*inv*wv.w);
  if (out) ((float4*)(out + (size_t)row * HID))[t] = o;
  if (out_bf) {
    bf16x4 ob; ob[0] = (__bf16)o.x; ob[1] = (__bf16)o.y; ob[2] = (__bf16)o.z; ob[3] = (__bf16)o.w;
    *(bf16x4*)(out_bf + (size_t)row * HID + t * 4) = ob;
  }
  if (out_h) {
    f16x4 oh, ol;
    const float e0 = o.x, e1 = o.y, e2 = o.z, e3 = o.w;
    oh[0] = (_Float16)e0; ol[0] = (_Float16)(e0 - (float)oh[0]);
    oh[1] = (_Float16)e1; ol[1] = (_Float16)(e1 - (float)oh[1]);
    oh[2] = (_Float16)e2; ol[2] = (_Float16)(e2 - (float)oh[2]);
    oh[3] = (_Float16)e3; ol[3] = (_Float16)(e3 - (float)oh[3]);
    *(f16x4*)(out_h + (size_t)row * HID + t * 4) = oh;
    *(f16x4*)(out_l + (size_t)row * HID + t * 4) = ol;
  }
}

// ---------------- fp32 -> bf16 convert ----------------
__global__ __launch_bounds__(256) void k_cvt_bf16(const float* __restrict__ in,
                                                  __bf16* __restrict__ out,
                                                  long n8) {
  const long i = ((long)blockIdx.x * 256 + threadIdx.x);
  if (i >= n8) return;
  const float4 a = *(const float4*)(in + i * 8);
  const float4 b = *(const float4*)(in + i * 8 + 4);
  bf16x8 o;
  o[0] = (__bf16)a.x; o[1] = (__bf16)a.y; o[2] = (__bf16)a.z; o[3] = (__bf16)a.w;
  o[4] = (__bf16)b.x; o[5] = (__bf16)b.y; o[6] = (__bf16)b.z; o[7] = (__bf16)b.w;
  *(bf16x8*)(out + i * 8) = o;
}

// ---------------- fp32 -> f16 hi/lo split ----------------
__global__ __launch_bounds__(256) void k_split_f16(const float* __restrict__ in,
                                                   _Float16* __restrict__ oh,
                                                   _Float16* __restrict__ ol,
                                                   long n8) {
  const long i = ((long)blockIdx.x * 256 + threadIdx.x);
  if (i >= n8) return;
  const float4 a = *(const float4*)(in + i * 8);
  const float4 b = *(const float4*)(in + i * 8 + 4);
  float e[8] = {a.x, a.y, a.z, a.w, b.x, b.y, b.z, b.w};
  f16x8 h, l;
  #pragma unroll
  for (int j = 0; j < 8; ++j) {
    h[j] = (_Float16)e[j];
    l[j] = (_Float16)(e[j] - (float)h[j]);
  }
  *(f16x8*)(oh + i * 8) = h;
  *(f16x8*)(ol + i * 8) = l;
}

// ---------------- split-f16 MFMA NT GEMM: C[M,N] = A*B^T (+res), fp32-accurate ----------------
// 128x128 tile, BK=32, 4 waves, 3 MFMAs per product (ah*bh + ah*bl + al*bh).
__global__ __launch_bounds__(256, 2) void k_lin(const _Float16* __restrict__ Ah,
                                                const _Float16* __restrict__ Al,
                                                const _Float16* __restrict__ Bh,
                                                const _Float16* __restrict__ Bl,
                                                const float* __restrict__ res,
                                                float* __restrict__ C,
                                                int N, int Kd) {
  const int m0 = blockIdx.y * 128, n0 = blockIdx.x * 128;
  __shared__ __align__(16) _Float16 Ash[128 * 32];
  __shared__ __align__(16) _Float16 Asl[128 * 32];
  __shared__ __align__(16) _Float16 Bsh[128 * 32];
  __shared__ __align__(16) _Float16 Bsl[128 * 32];
  const int t = threadIdx.x, lane = t & 63, w = t >> 6;
  const int wr = w & 1, wc = w >> 1;
  const int sr = t >> 2, sk = (t & 3) * 8;
  const size_t a0 = (size_t)(m0 + sr) * Kd, a1 = (size_t)(m0 + 64 + sr) * Kd;
  const size_t b0 = (size_t)(n0 + sr) * Kd, b1 = (size_t)(n0 + 64 + sr) * Kd;
  f32x4 acc[4][4];
  #pragma unroll
  for (int i = 0; i < 4; ++i)
    #pragma unroll
    for (int j = 0; j < 4; ++j) acc[i][j] = (f32x4)(0.f);

  for (int kk = 0; kk < Kd; kk += 32) {
    gld16(Ah + a0 + kk + sk, Ash + w * 512);
    gld16(Ah + a1 + kk + sk, Ash + 2048 + w * 512);
    gld16(Al + a0 + kk + sk, Asl + w * 512);
    gld16(Al + a1 + kk + sk, Asl + 2048 + w * 512);
    gld16(Bh + b0 + kk + sk, Bsh + w * 512);
    gld16(Bh + b1 + kk + sk, Bsh + 2048 + w * 512);
    gld16(Bl + b0 + kk + sk, Bsl + w * 512);
    gld16(Bl + b1 + kk + sk, Bsl + 2048 + w * 512);
    __syncthreads();
    const int fo = (lane & 15) * 32 + (lane >> 4) * 8;
    f16x8 ah[4], al[4], bh[4], bl[4];
    #pragma unroll
    for (int i = 0; i < 4; ++i) {
      ah[i] = *(const f16x8*)&Ash[(wr * 64 + i * 16) * 32 + fo];
      al[i] = *(const f16x8*)&Asl[(wr * 64 + i * 16) * 32 + fo];
      bh[i] = *(const f16x8*)&Bsh[(wc * 64 + i * 16) * 32 + fo];
      bl[i] = *(const f16x8*)&Bsl[(wc * 64 + i * 16) * 32 + fo];
    }
    #pragma unroll
    for (int i = 0; i < 4; ++i)
      #pragma unroll
      for (int j = 0; j < 4; ++j) {
        acc[i][j] = __builtin_amdgcn_mfma_f32_16x16x32_f16(al[i], bh[j], acc[i][j], 0, 0, 0);
        acc[i][j] = __builtin_amdgcn_mfma_f32_16x16x32_f16(ah[i], bl[j], acc[i][j], 0, 0, 0);
        acc[i][j] = __builtin_amdgcn_mfma_f32_16x16x32_f16(ah[i], bh[j], acc[i][j], 0, 0, 0);
      }
    __syncthreads();
  }
  const int cb = lane & 15, rb = (lane >> 4) * 4;
  #pragma unroll
  for (int i = 0; i < 4; ++i)
    #pragma unroll
    for (int r = 0; r < 4; ++r) {
      const int rr = m0 + wr * 64 + i * 16 + rb + r;
      #pragma unroll
      for (int j = 0; j < 4; ++j) {
        const int cc = n0 + wc * 64 + j * 16 + cb;
        float v = acc[i][j][r];
        if (res) v += res[(size_t)rr * N + cc];
        C[(size_t)rr * N + cc] = v;
      }
    }
}

// ---------------- RoPE (in-place on q,k inside qkv) ----------------
__global__ __launch_bounds__(256) void k_rope(float* __restrict__ qkv) {
  const int s = blockIdx.x, t = threadIdx.x;
  float* rowp = qkv + (size_t)s * QKVW;
  const float LOG10000 = 9.210340371976184f;
  #pragma unroll
  for (int it = 0; it < 4; ++it) {
    const int idx = it * 256 + t;
    const int hh = idx >> 6, d = idx & 63;
    const int i = d & 31;
    const float ang = (float)s * expf(-(float)i * (1.0f / 32.0f) * LOG10000);
    float cv, sv;
    sincosf(ang, &sv, &cv);
    float* qp = rowp + hh * HDIM;
    float* kp = rowp + HID + hh * HDIM;
    const int pd = (d < 32) ? d + 32 : d - 32;
    const float q0 = qp[d], q1 = qp[pd];
    const float k0 = kp[d], k1 = kp[pd];
    const float rq = (d < 32) ? -q1 : q1;
    const float rk = (d < 32) ? -k1 : k1;
    __syncthreads();
    qp[d] = q0 * cv + rq * sv;
    kp[d] = k0 * cv + rk * sv;
  }
}

// ---------------- flash attention fp32 (emits f16 hi/lo splits) ----------------
__global__ __launch_bounds__(256) void k_attn(const float* __restrict__ qkv,
                                              _Float16* __restrict__ attn_h,
                                              _Float16* __restrict__ attn_l) {
  const int h  = blockIdx.x;
  const int qt = (int)gridDim.y - 1 - (int)blockIdx.y;
  const int t  = threadIdx.x;
  const int qr = t >> 2, c = t & 3;
  const int qrow = qt * 64 + qr;

  __shared__ __align__(16) float ks[32][68];
  __shared__ __align__(16) float vs[32][68];
  __shared__ float sp[64][36];
  __shared__ float pm[64][4];
  __shared__ float psum_s[64][4];
  __shared__ float mS[64], lS[64], ccS[64];

  float qreg[64];
  {
    const float4* qp = (const float4*)(qkv + (size_t)qrow * QKVW + h * HDIM);
    #pragma unroll
    for (int i = 0; i < 16; ++i) {
      float4 v = qp[i];
      qreg[4*i+0] = v.x * 0.125f; qreg[4*i+1] = v.y * 0.125f;
      qreg[4*i+2] = v.z * 0.125f; qreg[4*i+3] = v.w * 0.125f;
    }
  }
  float oreg[16];
  #pragma unroll
  for (int i = 0; i < 16; ++i) oreg[i] = 0.f;
  if (c == 0) { mS[qr] = -INFINITY; lS[qr] = 0.f; }

  const int nkt = qt * 2 + 2;
  for (int kt = 0; kt < nkt; ++kt) {
    {
      const int row = t >> 3;
      const int col0 = (t & 7) * 8;
      const float* base = qkv + (size_t)(kt * 32 + row) * QKVW + HID + h * HDIM + col0;
      float4 kv0 = *(const float4*)(base);
      float4 kv1 = *(const float4*)(base + 4);
      float4 vv0 = *(const float4*)(base + HID);
      float4 vv1 = *(const float4*)(base + HID + 4);
      ks[row][col0+0]=kv0.x; ks[row][col0+1]=kv0.y; ks[row][col0+2]=kv0.z; ks[row][col0+3]=kv0.w;
      ks[row][col0+4]=kv1.x; ks[row][col0+5]=kv1.y; ks[row][col0+6]=kv1.z; ks[row][col0+7]=kv1.w;
      vs[row][col0+0]=vv0.x; vs[row][col0+1]=vv0.y; vs[row][col0+2]=vv0.z; vs[row][col0+3]=vv0.w;
      vs[row][col0+4]=vv1.x; vs[row][col0+5]=vv1.y; vs[row][col0+6]=vv1.z; vs[row][col0+7]=vv1.w;
    }
    __syncthreads();
    float svv[8]; float smax = -INFINITY;
    #pragma unroll
    for (int jj = 0; jj < 8; ++jj) {
      const int j = c + 4 * jj;
      float acc = 0.f;
      #pragma unroll
      for (int dd = 0; dd < 16; ++dd) {
        float4 kv = *(const float4*)&ks[j][dd * 4];
        acc += qreg[4*dd+0]*kv.x + qreg[4*dd+1]*kv.y + qreg[4*dd+2]*kv.z + qreg[4*dd+3]*kv.w;
      }
      if (kt * 32 + j > qrow) acc = -INFINITY;
      svv[jj] = acc;
      smax = fmaxf(smax, acc);
    }
    pm[qr][c] = smax;
    __syncthreads();
    if (c == 0) {
      const float mold = mS[qr];
      const float mnew = fmaxf(mold, fmaxf(fmaxf(pm[qr][0], pm[qr][1]), fmaxf(pm[qr][2], pm[qr][3])));
      mS[qr] = mnew;
      ccS[qr] = expf(mold - mnew);
    }
    __syncthreads();
    const float mnew = mS[qr];
    const float corr = ccS[qr];
    float psum = 0.f;
    #pragma unroll
    for (int jj = 0; jj < 8; ++jj) {
      const int j = c + 4 * jj;
      const float p = expf(svv[jj] - mnew);
      sp[qr][j] = p;
      psum += p;
    }
    psum_s[qr][c] = psum;
    #pragma unroll
    for (int i = 0; i < 16; ++i) oreg[i] *= corr;
    __syncthreads();
    if (c == 0)
      lS[qr] = lS[qr] * corr + psum_s[qr][0] + psum_s[qr][1] + psum_s[qr][2] + psum_s[qr][3];
    #pragma unroll
    for (int j = 0; j < 32; ++j) {
      const float p = sp[qr][j];
      const float4* vr = (const float4*)&vs[j][c * 16];
      float4 v0 = vr[0], v1 = vr[1], v2 = vr[2], v3 = vr[3];
      oreg[0]  += p*v0.x; oreg[1]  += p*v0.y; oreg[2]  += p*v0.z; oreg[3]  += p*v0.w;
      oreg[4]  += p*v1.x; oreg[5]  += p*v1.y; oreg[6]  += p*v1.z; oreg[7]  += p*v1.w;
      oreg[8]  += p*v2.x; oreg[9]  += p*v2.y; oreg[10] += p*v2.z; oreg[11] += p*v2.w;
      oreg[12] += p*v3.x; oreg[13] += p*v3.y; oreg[14] += p*v3.z; oreg[15] += p*v3.w;
    }
    __syncthreads();
  }
  const float inv = 1.0f / lS[qr];
  const size_t ob = (size_t)qrow * HID + h * HDIM + c * 16;
  f16x8 oh0, ol0, oh1, ol1;
  #pragma unroll
  for (int i = 0; i < 8; ++i) {
    const float v = oreg[i] * inv;
    oh0[i] = (_Float16)v; ol0[i] = (_Float16)(v - (float)oh0[i]);
  }
  #pragma unroll
  for (int i = 0; i < 8; ++i) {
    const float v = oreg[8 + i] * inv;
    oh1[i] = (_Float16)v; ol1[i] = (_Float16)(v - (float)oh1[i]);
  }
  *(f16x8*)(attn_h + ob) = oh0;
  *(f16x8*)(attn_h + ob + 8) = oh1;
  *(f16x8*)(attn_l + ob) = ol0;
  *(f16x8*)(attn_l + ob + 8) = ol1;
}

// ---------------- router (fp32, discrete top-2 must match reference) ----------------
__global__ __launch_bounds__(64) void k_router(const float* __restrict__ xn2,
                                               const float* __restrict__ rw,
                                               int* __restrict__ tidx,
                                               float* __restrict__ tw) {
  const int n = blockIdx.x, lane = threadIdx.x;
  float lg[8] = {0.f,0.f,0.f,0.f,0.f,0.f,0.f,0.f};
  #pragma unroll
  for (int i = 0; i < 4; ++i) {
    float4 xv = ((const float4*)(xn2 + (size_t)n * HID))[lane + 64 * i];
    #pragma unroll
    for (int e = 0; e < 8; ++e) {
      float4 wv = ((const float4*)(rw + (size_t)e * HID))[lane + 64 * i];
      lg[e] += xv.x*wv.x + xv.y*wv.y + xv.z*wv.z + xv.w*wv.w;
    }
  }
  #pragma unroll
  for (int e = 0; e < 8; ++e) {
    #pragma unroll
    for (int off = 32; off; off >>= 1) lg[e] += __shfl_xor(lg[e], off);
  }
  if (lane == 0) {
    int e1 = 0; float l1 = lg[0];
    #pragma unroll
    for (int e = 1; e < 8; ++e) if (lg[e] > l1) { l1 = lg[e]; e1 = e; }
    int e2 = -1; float l2 = -INFINITY;
    #pragma unroll
    for (int e = 0; e < 8; ++e) if (e != e1 && lg[e] > l2) { l2 = lg[e]; e2 = e; }
    const float w1 = 1.0f / (1.0f + expf(l2 - l1));
    tidx[n * 2] = e1; tidx[n * 2 + 1] = e2;
    tw[n * 2] = w1;  tw[n * 2 + 1] = 1.0f - w1;
  }
}

// ---------------- capacity scan + aux loss ----------------
__global__ __launch_bounds__(512) void k_scan(const int* __restrict__ tidx,
                                              int* __restrict__ slotk,
                                              int* __restrict__ perm,
                                              int* __restrict__ counts,
                                              float* __restrict__ aux_out) {
  const int t = threadIdx.x;
  const int e = t >> 6, lane = t & 63;
  __shared__ int cls[8];
  int offset = 0;
  for (int chunk = 0; chunk < SEQ / 64; ++chunk) {
    const int n = chunk * 64 + lane;
    const int i0 = tidx[n * 2], i1 = tidx[n * 2 + 1];
    const bool bit = (i0 == e) || (i1 == e);
    const unsigned long long mask = __ballot(bit);
    const int pos = offset + __popcll(mask & ((1ull << lane) - 1ull));
    if (bit) {
      const int kk = (i0 == e) ? 0 : 1;
      slotk[n * 2 + kk] = pos;
      if (pos < CAPE) perm[e * CAPE + pos] = n;
    }
    offset += __popcll(mask);
  }
  if (lane == 0) { counts[e] = offset; cls[e] = offset; }
  __syncthreads();
  if (t == 0) {
    float mean = 0.f;
    for (int i = 0; i < 8; ++i) mean += (float)cls[i];
    mean /= (8.0f * (float)SEQ);
    float var = 0.f;
    for (int i = 0; i < 8; ++i) {
      const float f = (float)cls[i] / (float)SEQ;
      var += (f - mean) * (f - mean);
    }
    var /= 7.0f;
    aux_out[0] = var * 8.0f;
  }
}

// ---------------- MoE gate/up: bf16 MFMA ----------------
__global__ __launch_bounds__(256, 2) void k_moe_gu(const __bf16* __restrict__ X,
                                                   const __bf16* __restrict__ Wg,
                                                   const __bf16* __restrict__ Wu,
                                                   const int* __restrict__ perm,
                                                   const int* __restrict__ counts,
                                                   __bf16* __restrict__ act) {
  const int e = blockIdx.z;
  const int rows = min(counts[e], CAPE);
  const int m0 = blockIdx.y * 128;
  if (m0 >= rows) return;
  const int n0 = blockIdx.x * 128;
  __shared__ __align__(16) __bf16 As[128 * 32];
  __shared__ __align__(16) __bf16 Bgs[128 * 32];
  __shared__ __align__(16) __bf16 Bus[128 * 32];
  const int t = threadIdx.x;
  const int lane = t & 63, w = t >> 6;
  const int wr = w & 1, wc = w >> 1;
  const int sr = t >> 2;
  const int sk = (t & 3) * 8;
  const int gr0 = m0 + sr, gr1 = m0 + 64 + sr;
  const size_t arow0 = (size_t)((gr0 < rows) ? perm[e * CAPE + gr0] : 0) * HID;
  const size_t arow1 = (size_t)((gr1 < rows) ? perm[e * CAPE + gr1] : 0) * HID;
  const __bf16* gB = Wg + (size_t)e * IDIM * HID;
  const __bf16* uB = Wu + (size_t)e * IDIM * HID;
  const size_t brow0 = (size_t)(n0 + sr) * HID, brow1 = (size_t)(n0 + 64 + sr) * HID;
  f32x4 accg[4][4], accu[4][4];
  #pragma unroll
  for (int i = 0; i < 4; ++i)
    #pragma unroll
    for (int j = 0; j < 4; ++j) { accg[i][j] = (f32x4)(0.f); accu[i][j] = (f32x4)(0.f); }

  for (int kk = 0; kk < HID; kk += 32) {
    gld16(X + arow0 + kk + sk, As + w * 512);
    gld16(X + arow1 + kk + sk, As + 2048 + w * 512);
    gld16(gB + brow0 + kk + sk, Bgs + w * 512);
    gld16(gB + brow1 + kk + sk, Bgs + 2048 + w * 512);
    gld16(uB + brow0 + kk + sk, Bus + w * 512);
    gld16(uB + brow1 + kk + sk, Bus + 2048 + w * 512);
    __syncthreads();
    bf16x8 a[4], bg[4], bu[4];
    #pragma unroll
    for (int i = 0; i < 4; ++i) {
      const int fo = (lane & 15) * 32 + (lane >> 4) * 8;
      a[i]  = *(const bf16x8*)&As[(wr * 64 + i * 16) * 32 + fo];
      bg[i] = *(const bf16x8*)&Bgs[(wc * 64 + i * 16) * 32 + fo];
      bu[i] = *(const bf16x8*)&Bus[(wc * 64 + i * 16) * 32 + fo];
    }
    #pragma unroll
    for (int i = 0; i < 4; ++i)
      #pragma unroll
      for (int j = 0; j < 4; ++j) {
        accg[i][j] = __builtin_amdgcn_mfma_f32_16x16x32_bf16(a[i], bg[j], accg[i][j], 0, 0, 0);
        accu[i][j] = __builtin_amdgcn_mfma_f32_16x16x32_bf16(a[i], bu[j], accu[i][j], 0, 0, 0);
      }
    __syncthreads();
  }
  const int cb = lane & 15, rb = (lane >> 4) * 4;
  #pragma unroll
  for (int i = 0; i < 4; ++i)
    #pragma unroll
    for (int r = 0; r < 4; ++r) {
      const int rr = m0 + wr * 64 + i * 16 + rb + r;
      if (rr < rows) {
        #pragma unroll
        for (int j = 0; j < 4; ++j) {
          const float g = accg[i][j][r], u = accu[i][j][r];
          const float v = g / (1.f + expf(-g)) * u;
          act[((size_t)e * CAPE + rr) * IDIM + n0 + wc * 64 + j * 16 + cb] = (__bf16)v;
        }
      }
    }
}

// ---------------- MoE down: bf16 MFMA ----------------
__global__ __launch_bounds__(256, 2) void k_moe_down(const __bf16* __restrict__ act,
                                                     const __bf16* __restrict__ Wd,
                                                     const int* __restrict__ counts,
                                                     float* __restrict__ y) {
  const int e = blockIdx.z;
  const int rows = min(counts[e], CAPE);
  const int m0 = blockIdx.y * 128;
  if (m0 >= rows) return;
  const int n0 = blockIdx.x * 128;
  __shared__ __align__(16) __bf16 As[128 * 32];
  __shared__ __align__(16) __bf16 Bs[128 * 32];
  const int t = threadIdx.x;
  const int lane = t & 63, w = t >> 6;
  const int wr = w & 1, wc = w >> 1;
  const int sr = t >> 2;
  const int sk = (t & 3) * 8;
  const __bf16* Ab = act + ((size_t)e * CAPE) * IDIM;
  const __bf16* Bb = Wd + (size_t)e * HID * IDIM;
  const size_t arow0 = (size_t)(m0 + sr) * IDIM, arow1 = (size_t)(m0 + 64 + sr) * IDIM;
  const size_t brow0 = (size_t)(n0 + sr) * IDIM, brow1 = (size_t)(n0 + 64 + sr) * IDIM;
  f32x4 acc[4][4];
  #pragma unroll
  for (int i = 0; i < 4; ++i)
    #pragma unroll
    for (int j = 0; j < 4; ++j) acc[i][j] = (f32x4)(0.f);

  for (int kk = 0; kk < IDIM; kk += 32) {
    gld16(Ab + arow0 + kk + sk, As + w * 512);
    gld16(Ab + arow1 + kk + sk, As + 2048 + w * 512);
    gld16(Bb + brow0 + kk + sk, Bs + w * 512);
    gld16(Bb + brow1 + kk + sk, Bs + 2048 + w * 512);
    __syncthreads();
    bf16x8 a[4], b[4];
    #pragma unroll
    for (int i = 0; i < 4; ++i) {
      const int fo = (lane & 15) * 32 + (lane >> 4) * 8;
      a[i] = *(const bf16x8*)&As[(wr * 64 + i * 16) * 32 + fo];
      b[i] = *(const bf16x8*)&Bs[(wc * 64 + i * 16) * 32 + fo];
    }
    #pragma unroll
    for (int i = 0; i < 4; ++i)
      #pragma unroll
      for (int j = 0; j < 4; ++j)
        acc[i][j] = __builtin_amdgcn_mfma_f32_16x16x32_bf16(a[i], b[j], acc[i][j], 0, 0, 0);
    __syncthreads();
  }
  const int cb = lane & 15, rb = (lane >> 4) * 4;
  #pragma unroll
  for (int i = 0; i < 4; ++i)
    #pragma unroll
    for (int r = 0; r < 4; ++r) {
      const int rr = m0 + wr * 64 + i * 16 + rb + r;
      if (rr < rows) {
        #pragma unroll
        for (int j = 0; j < 4; ++j)
          y[((size_t)e * CAPE + rr) * HID + n0 + wc * 64 + j * 16 + cb] = acc[i][j][r];
      }
    }
}

// ---------------- combine ----------------
__global__ __launch_bounds__(256) void k_combine(const float* __restrict__ x1,
                                                 const float* __restrict__ y,
                                                 const int* __restrict__ tidx,
                                                 const float* __restrict__ tw,
                                                 const int* __restrict__ slotk,
                                                 float* __restrict__ out) {
  const int n = blockIdx.x, t = threadIdx.x;
  float4 acc = ((const float4*)(x1 + (size_t)n * HID))[t];
  #pragma unroll
  for (int k = 0; k < 2; ++k) {
    const int slot = slotk[n * 2 + k];
    if (slot < CAPE) {
      const int e = tidx[n * 2 + k];
      const float w = tw[n * 2 + k];
      float4 v = ((const float4*)(y + ((size_t)e * CAPE + slot) * HID))[t];
      acc.x += w * v.x; acc.y += w * v.y; acc.z += w * v.z; acc.w += w * v.w;
    }
  }
  ((float4*)(out + (size_t)n * HID))[t] = acc;
}

extern "C" void kernel_launch(void* const* d_in, const int* in_sizes, int n_in,
                              void* d_out, int out_size, void* d_ws, size_t ws_size,
                              hipStream_t stream) {
  const float* x     = (const float*)d_in[0];
  const float* anw   = (const float*)d_in[1];
  const float* qkv_w = (const float*)d_in[2];
  const float* o_w   = (const float*)d_in[3];
  const float* fnw   = (const float*)d_in[4];
  const float* rw    = (const float*)d_in[5];
  const float* wg    = (const float*)d_in[6];
  const float* wu    = (const float*)d_in[7];
  const float* wd    = (const float*)d_in[8];
  (void)in_sizes; (void)n_in; (void)out_size; (void)ws_size;
  float* out = (float*)d_out;

  float* ws = (float*)d_ws;
  size_t off = 0;
  float* qkv  = ws + off; off += (size_t)SEQ * QKVW;
  float* x1   = ws + off; off += (size_t)SEQ * HID;
  float* xn2  = ws + off; off += (size_t)SEQ * HID;
  float* ybuf = ws + off; off += (size_t)NEXP * CAPE * HID;
  float* tw   = ws + off; off += SEQ * 2;
  int* tidx   = (int*)(ws + off); off += SEQ * 2;
  int* slotk  = (int*)(ws + off); off += SEQ * 2;
  int* perm   = (int*)(ws + off); off += NEXP * CAPE;
  int* counts = (int*)(ws + off); off += 16;
  // 2-byte element region
  __bf16* bfbase = (__bf16*)(ws + off);
  size_t boff = 0;
  __bf16* xn2_bf = bfbase + boff; boff += (size_t)SEQ * HID;
  __bf16* wg_bf  = bfbase + boff; boff += (size_t)NEXP * IDIM * HID;
  __bf16* wu_bf  = bfbase + boff; boff += (size_t)NEXP * IDIM * HID;
  __bf16* wd_bf  = bfbase + boff; boff += (size_t)NEXP * HID * IDIM;
  __bf16* act_bf = bfbase + boff; boff += (size_t)NEXP * CAPE * IDIM;
  _Float16* f16base = (_Float16*)(bfbase + boff);
  size_t foff = 0;
  _Float16* xn_h   = f16base + foff; foff += (size_t)SEQ * HID;
  _Float16* xn_l   = f16base + foff; foff += (size_t)SEQ * HID;
  _Float16* qkvw_h = f16base + foff; foff += (size_t)QKVW * HID;
  _Float16* qkvw_l = f16base + foff; foff += (size_t)QKVW * HID;
  _Float16* attn_h = f16base + foff; foff += (size_t)SEQ * HID;
  _Float16* attn_l = f16base + foff; foff += (size_t)SEQ * HID;
  _Float16* ow_h   = f16base + foff; foff += (size_t)HID * HID;
  _Float16* ow_l   = f16base + foff; foff += (size_t)HID * HID;

  const long nw8 = (long)NEXP * IDIM * HID / 8;
  const int cvtGrid = (int)((nw8 + 255) / 256);
  k_cvt_bf16<<<cvtGrid, 256, 0, stream>>>(wg, wg_bf, nw8);
  k_cvt_bf16<<<cvtGrid, 256, 0, stream>>>(wu, wu_bf, nw8);
  k_cvt_bf16<<<cvtGrid, 256, 0, stream>>>(wd, wd_bf, nw8);
  k_split_f16<<<(QKVW * HID / 8 + 255) / 256, 256, 0, stream>>>(qkv_w, qkvw_h, qkvw_l, QKVW * HID / 8);
  k_split_f16<<<(HID * HID / 8 + 255) / 256, 256, 0, stream>>>(o_w, ow_h, ow_l, HID * HID / 8);

  k_rmsnorm<<<SEQ, 256, 0, stream>>>(x, anw, nullptr, nullptr, xn_h, xn_l);
  k_lin<<<dim3(QKVW / 128, SEQ / 128), 256, 0, stream>>>(xn_h, xn_l, qkvw_h, qkvw_l, nullptr, qkv, QKVW, HID);
  k_rope<<<SEQ, 256, 0, stream>>>(qkv);
  k_attn<<<dim3(NHEAD, SEQ / 64), 256, 0, stream>>>(qkv, attn_h, attn_l);
  k_lin<<<dim3(HID / 128, SEQ / 128), 256, 0, stream>>>(attn_h, attn_l, ow_h, ow_l, x, x1, HID, HID);
  k_rmsnorm<<<SEQ, 256, 0, stream>>>(x1, fnw, xn2, xn2_bf, nullptr, nullptr);
  k_router<<<SEQ, 64, 0, stream>>>(xn2, rw, tidx, tw);
  k_scan<<<1, 512, 0, stream>>>(tidx, slotk, perm, counts, out + (size_t)SEQ * HID);
  k_moe_gu<<<dim3(IDIM / 128, CAPE / 128, NEXP), 256, 0, stream>>>(xn2_bf, wg_bf, wu_bf, perm, counts, act_bf);
  k_moe_down<<<dim3(HID / 128, CAPE / 128, NEXP), 256, 0, stream>>>(act_bf, wd_bf, counts, ybuf);
  k_combine<<<SEQ, 256, 0, stream>>>(x1, ybuf, tidx, tw, slotk, out);
}

// Round 4
// 871.043 us; speedup vs baseline: 2.8734x; 1.2734x over previous
//
#include <hip/hip_runtime.h>
#include <math.h>

#define SEQ   2048
#define HID   1024
#define NHEAD 16
#define HDIM  64
#define NEXP  8
#define IDIM  4096
#define CAPE  1024
#define QKVW  3072

typedef __bf16    bf16x8 __attribute__((ext_vector_type(8)));
typedef __bf16    bf16x4 __attribute__((ext_vector_type(4)));
typedef _Float16  f16x8  __attribute__((ext_vector_type(8)));
typedef _Float16  f16x4  __attribute__((ext_vector_type(4)));
typedef float     f32x4  __attribute__((ext_vector_type(4)));

__device__ __forceinline__ void gld16(const void* g, void* l) {
  __builtin_amdgcn_global_load_lds((const __attribute__((address_space(1))) void*)g,
                                   (__attribute__((address_space(3))) void*)l, 16, 0, 0);
}

// ---------------- RMSNorm: fp32 out (opt), bf16 out (opt), f16 hi/lo out (opt) ----------------
__global__ __launch_bounds__(256) void k_rmsnorm(const float* __restrict__ x,
                                                 const float* __restrict__ w,
                                                 float* __restrict__ out,
                                                 __bf16* __restrict__ out_bf,
                                                 _Float16* __restrict__ out_h,
                                                 _Float16* __restrict__ out_l) {
  const int row = blockIdx.x, t = threadIdx.x;
  float4 v = ((const float4*)(x + (size_t)row * HID))[t];
  float ss = v.x*v.x + v.y*v.y + v.z*v.z + v.w*v.w;
  #pragma unroll
  for (int off = 32; off; off >>= 1) ss += __shfl_down(ss, off);
  __shared__ float red[4];
  if ((t & 63) == 0) red[t >> 6] = ss;
  __syncthreads();
  const float inv = rsqrtf((red[0] + red[1] + red[2] + red[3]) * (1.0f / HID) + 1e-6f);
  float4 wv = ((const float4*)w)[t];
  float4 o = make_float4(v.x*inv*wv.x, v.y*inv*wv.y, v.z*inv*wv.z, v.w*inv*wv.w);
  if (out) ((float4*)(out + (size_t)row * HID))[t] = o;
  if (out_bf) {
    bf16x4 ob; ob[0] = (__bf16)o.x; ob[1] = (__bf16)o.y; ob[2] = (__bf16)o.z; ob[3] = (__bf16)o.w;
    *(bf16x4*)(out_bf + (size_t)row * HID + t * 4) = ob;
  }
  if (out_h) {
    f16x4 oh, ol;
    const float e0 = o.x, e1 = o.y, e2 = o.z, e3 = o.w;
    oh[0] = (_Float16)e0; ol[0] = (_Float16)(e0 - (float)oh[0]);
    oh[1] = (_Float16)e1; ol[1] = (_Float16)(e1 - (float)oh[1]);
    oh[2] = (_Float16)e2; ol[2] = (_Float16)(e2 - (float)oh[2]);
    oh[3] = (_Float16)e3; ol[3] = (_Float16)(e3 - (float)oh[3]);
    *(f16x4*)(out_h + (size_t)row * HID + t * 4) = oh;
    *(f16x4*)(out_l + (size_t)row * HID + t * 4) = ol;
  }
}

// ---------------- fp32 -> bf16 convert ----------------
__global__ __launch_bounds__(256) void k_cvt_bf16(const float* __restrict__ in,
                                                  __bf16* __restrict__ out,
                                                  long n8) {
  const long i = ((long)blockIdx.x * 256 + threadIdx.x);
  if (i >= n8) return;
  const float4 a = *(const float4*)(in + i * 8);
  const float4 b = *(const float4*)(in + i * 8 + 4);
  bf16x8 o;
  o[0] = (__bf16)a.x; o[1] = (__bf16)a.y; o[2] = (__bf16)a.z; o[3] = (__bf16)a.w;
  o[4] = (__bf16)b.x; o[5] = (__bf16)b.y; o[6] = (__bf16)b.z; o[7] = (__bf16)b.w;
  *(bf16x8*)(out + i * 8) = o;
}

// ---------------- fp32 -> f16 hi/lo split ----------------
__global__ __launch_bounds__(256) void k_split_f16(const float* __restrict__ in,
                                                   _Float16* __restrict__ oh,
                                                   _Float16* __restrict__ ol,
                                                   long n8) {
  const long i = ((long)blockIdx.x * 256 + threadIdx.x);
  if (i >= n8) return;
  const float4 a = *(const float4*)(in + i * 8);
  const float4 b = *(const float4*)(in + i * 8 + 4);
  float e[8] = {a.x, a.y, a.z, a.w, b.x, b.y, b.z, b.w};
  f16x8 h, l;
  #pragma unroll
  for (int j = 0; j < 8; ++j) {
    h[j] = (_Float16)e[j];
    l[j] = (_Float16)(e[j] - (float)h[j]);
  }
  *(f16x8*)(oh + i * 8) = h;
  *(f16x8*)(ol + i * 8) = l;
}

// ---------------- split-f16 MFMA NT GEMM ----------------
__global__ __launch_bounds__(256, 2) void k_lin(const _Float16* __restrict__ Ah,
                                                const _Float16* __restrict__ Al,
                                                const _Float16* __restrict__ Bh,
                                                const _Float16* __restrict__ Bl,
                                                const float* __restrict__ res,
                                                float* __restrict__ C,
                                                int N, int Kd) {
  const int m0 = blockIdx.y * 128, n0 = blockIdx.x * 128;
  __shared__ __align__(16) _Float16 Ash[128 * 32];
  __shared__ __align__(16) _Float16 Asl[128 * 32];
  __shared__ __align__(16) _Float16 Bsh[128 * 32];
  __shared__ __align__(16) _Float16 Bsl[128 * 32];
  const int t = threadIdx.x, lane = t & 63, w = t >> 6;
  const int wr = w & 1, wc = w >> 1;
  const int sr = t >> 2, sk = (t & 3) * 8;
  const size_t a0 = (size_t)(m0 + sr) * Kd, a1 = (size_t)(m0 + 64 + sr) * Kd;
  const size_t b0 = (size_t)(n0 + sr) * Kd, b1 = (size_t)(n0 + 64 + sr) * Kd;
  f32x4 acc[4][4];
  #pragma unroll
  for (int i = 0; i < 4; ++i)
    #pragma unroll
    for (int j = 0; j < 4; ++j) acc[i][j] = (f32x4)(0.f);

  for (int kk = 0; kk < Kd; kk += 32) {
    gld16(Ah + a0 + kk + sk, Ash + w * 512);
    gld16(Ah + a1 + kk + sk, Ash + 2048 + w * 512);
    gld16(Al + a0 + kk + sk, Asl + w * 512);
    gld16(Al + a1 + kk + sk, Asl + 2048 + w * 512);
    gld16(Bh + b0 + kk + sk, Bsh + w * 512);
    gld16(Bh + b1 + kk + sk, Bsh + 2048 + w * 512);
    gld16(Bl + b0 + kk + sk, Bsl + w * 512);
    gld16(Bl + b1 + kk + sk, Bsl + 2048 + w * 512);
    __syncthreads();
    const int fo = (lane & 15) * 32 + (lane >> 4) * 8;
    f16x8 ah[4], al[4], bh[4], bl[4];
    #pragma unroll
    for (int i = 0; i < 4; ++i) {
      ah[i] = *(const f16x8*)&Ash[(wr * 64 + i * 16) * 32 + fo];
      al[i] = *(const f16x8*)&Asl[(wr * 64 + i * 16) * 32 + fo];
      bh[i] = *(const f16x8*)&Bsh[(wc * 64 + i * 16) * 32 + fo];
      bl[i] = *(const f16x8*)&Bsl[(wc * 64 + i * 16) * 32 + fo];
    }
    #pragma unroll
    for (int i = 0; i < 4; ++i)
      #pragma unroll
      for (int j = 0; j < 4; ++j) {
        acc[i][j] = __builtin_amdgcn_mfma_f32_16x16x32_f16(al[i], bh[j], acc[i][j], 0, 0, 0);
        acc[i][j] = __builtin_amdgcn_mfma_f32_16x16x32_f16(ah[i], bl[j], acc[i][j], 0, 0, 0);
        acc[i][j] = __builtin_amdgcn_mfma_f32_16x16x32_f16(ah[i], bh[j], acc[i][j], 0, 0, 0);
      }
    __syncthreads();
  }
  const int cb = lane & 15, rb = (lane >> 4) * 4;
  #pragma unroll
  for (int i = 0; i < 4; ++i)
    #pragma unroll
    for (int r = 0; r < 4; ++r) {
      const int rr = m0 + wr * 64 + i * 16 + rb + r;
      #pragma unroll
      for (int j = 0; j < 4; ++j) {
        const int cc = n0 + wc * 64 + j * 16 + cb;
        float v = acc[i][j][r];
        if (res) v += res[(size_t)rr * N + cc];
        C[(size_t)rr * N + cc] = v;
      }
    }
}

// ---------------- prep: RoPE + q-scale + f16 hi/lo split of Q,K; V transpose+split ----------------
// Q,K out: [NH][S][64]; Vt out: [NH][64][S]
__global__ __launch_bounds__(256) void k_prep(const float* __restrict__ qkv,
                                              _Float16* __restrict__ Qh, _Float16* __restrict__ Ql,
                                              _Float16* __restrict__ Kh, _Float16* __restrict__ Kl,
                                              _Float16* __restrict__ Vth, _Float16* __restrict__ Vtl) {
  const int h = blockIdx.x, s0 = blockIdx.y * 64;
  const int t = threadIdx.x;
  const int sl = t >> 2, qd = t & 3;
  const int s = s0 + sl;
  const float* base = qkv + (size_t)s * QKVW + h * HDIM;
  __shared__ float vt[64][65];

  // V into LDS (fp32)
  {
    const float* vb = base + 2 * HID + qd * 16;
    #pragma unroll
    for (int c = 0; c < 4; ++c) {
      float4 v = *(const float4*)(vb + c * 4);
      vt[sl][qd * 16 + c * 4 + 0] = v.x;
      vt[sl][qd * 16 + c * 4 + 1] = v.y;
      vt[sl][qd * 16 + c * 4 + 2] = v.z;
      vt[sl][qd * 16 + c * 4 + 3] = v.w;
    }
  }

  // RoPE for q,k: this thread handles dim pairs (d0+i, d0+i+32), i=0..7
  const int d0 = qd * 8;
  const float LOG10000 = 9.210340371976184f;
  float cv[8], sv[8];
  #pragma unroll
  for (int i = 0; i < 8; ++i) {
    const float ang = (float)s * expf(-(float)(d0 + i) * (1.0f / 32.0f) * LOG10000);
    sincosf(ang, &sv[i], &cv[i]);
  }
  float qa[8], qb[8], ka[8], kb[8];
  {
    float4 x0 = *(const float4*)(base + d0), x1 = *(const float4*)(base + d0 + 4);
    float4 y0 = *(const float4*)(base + d0 + 32), y1 = *(const float4*)(base + d0 + 36);
    qa[0]=x0.x; qa[1]=x0.y; qa[2]=x0.z; qa[3]=x0.w; qa[4]=x1.x; qa[5]=x1.y; qa[6]=x1.z; qa[7]=x1.w;
    qb[0]=y0.x; qb[1]=y0.y; qb[2]=y0.z; qb[3]=y0.w; qb[4]=y1.x; qb[5]=y1.y; qb[6]=y1.z; qb[7]=y1.w;
    const float* kbase = base + HID;
    float4 z0 = *(const float4*)(kbase + d0), z1 = *(const float4*)(kbase + d0 + 4);
    float4 w0 = *(const float4*)(kbase + d0 + 32), w1 = *(const float4*)(kbase + d0 + 36);
    ka[0]=z0.x; ka[1]=z0.y; ka[2]=z0.z; ka[3]=z0.w; ka[4]=z1.x; ka[5]=z1.y; ka[6]=z1.z; ka[7]=z1.w;
    kb[0]=w0.x; kb[1]=w0.y; kb[2]=w0.z; kb[3]=w0.w; kb[4]=w1.x; kb[5]=w1.y; kb[6]=w1.z; kb[7]=w1.w;
  }
  f16x8 qh_a, ql_a, qh_b, ql_b, kh_a, kl_a, kh_b, kl_b;
  #pragma unroll
  for (int i = 0; i < 8; ++i) {
    const float q1 = (qa[i] * cv[i] - qb[i] * sv[i]) * 0.125f;
    const float q2 = (qb[i] * cv[i] + qa[i] * sv[i]) * 0.125f;
    const float k1 = ka[i] * cv[i] - kb[i] * sv[i];
    const float k2 = kb[i] * cv[i] + ka[i] * sv[i];
    qh_a[i] = (_Float16)q1; ql_a[i] = (_Float16)(q1 - (float)qh_a[i]);
    qh_b[i] = (_Float16)q2; ql_b[i] = (_Float16)(q2 - (float)qh_b[i]);
    kh_a[i] = (_Float16)k1; kl_a[i] = (_Float16)(k1 - (float)kh_a[i]);
    kh_b[i] = (_Float16)k2; kl_b[i] = (_Float16)(k2 - (float)kh_b[i]);
  }
  const size_t qko = ((size_t)h * SEQ + s) * 64;
  *(f16x8*)(Qh + qko + d0) = qh_a;      *(f16x8*)(Qh + qko + d0 + 32) = qh_b;
  *(f16x8*)(Ql + qko + d0) = ql_a;      *(f16x8*)(Ql + qko + d0 + 32) = ql_b;
  *(f16x8*)(Kh + qko + d0) = kh_a;      *(f16x8*)(Kh + qko + d0 + 32) = kh_b;
  *(f16x8*)(Kl + qko + d0) = kl_a;      *(f16x8*)(Kl + qko + d0 + 32) = kl_b;

  __syncthreads();
  // V transpose out: thread covers dim d = t>>2, tokens sc..sc+16
  {
    const int d = t >> 2, sc = (t & 3) * 16;
    f16x8 vh0, vl0, vh1, vl1;
    #pragma unroll
    for (int j = 0; j < 8; ++j) {
      const float v = vt[sc + j][d];
      vh0[j] = (_Float16)v; vl0[j] = (_Float16)(v - (float)vh0[j]);
    }
    #pragma unroll
    for (int j = 0; j < 8; ++j) {
      const float v = vt[sc + 8 + j][d];
      vh1[j] = (_Float16)v; vl1[j] = (_Float16)(v - (float)vh1[j]);
    }
    const size_t vo = ((size_t)h * HDIM + d) * SEQ + s0 + sc;
    *(f16x8*)(Vth + vo) = vh0; *(f16x8*)(Vth + vo + 8) = vh1;
    *(f16x8*)(Vtl + vo) = vl0; *(f16x8*)(Vtl + vo + 8) = vl1;
  }
}

// ---------------- MFMA flash attention, split-f16 (fp32-equivalent) ----------------
// block = (head, 64-q tile); 4 waves x 16 q-rows; 64-key tiles.
__global__ __launch_bounds__(256) void k_attn2(
    const _Float16* __restrict__ Qh, const _Float16* __restrict__ Ql,
    const _Float16* __restrict__ Kh, const _Float16* __restrict__ Kl,
    const _Float16* __restrict__ Vth, const _Float16* __restrict__ Vtl,
    _Float16* __restrict__ attn_h, _Float16* __restrict__ attn_l) {
  const int h = blockIdx.x;
  const int qt = (int)gridDim.y - 1 - (int)blockIdx.y;   // heavy tiles first
  const int t = threadIdx.x, lane = t & 63, w = t >> 6;
  const int m_ = lane & 15, quad = lane >> 4;

  __shared__ __align__(16) _Float16 Ksh[2][64][32];   // [dim chunk][key][32 dims]
  __shared__ __align__(16) _Float16 Ksl[2][64][32];
  __shared__ __align__(16) _Float16 Vsh[4][64][16];   // [key group][dim][16 keys]
  __shared__ __align__(16) _Float16 Vsl[4][64][16];
  __shared__ __align__(16) _Float16 Ph[4][16][72];    // per-wave P, padded pitch
  __shared__ __align__(16) _Float16 Pl[4][16][72];

  const int q0 = qt * 64 + w * 16;
  const _Float16* qbh = Qh + ((size_t)h * SEQ + q0 + m_) * 64 + quad * 8;
  const _Float16* qbl = Ql + ((size_t)h * SEQ + q0 + m_) * 64 + quad * 8;
  const f16x8 qh0 = *(const f16x8*)(qbh);
  const f16x8 qh1 = *(const f16x8*)(qbh + 32);
  const f16x8 ql0 = *(const f16x8*)(qbl);
  const f16x8 ql1 = *(const f16x8*)(qbl + 32);

  f32x4 o[4];
  #pragma unroll
  for (int nt = 0; nt < 4; ++nt) o[nt] = (f32x4)(0.f);
  float m_r[4] = {-1e30f, -1e30f, -1e30f, -1e30f};
  float l_r[4] = {0.f, 0.f, 0.f, 0.f};

  for (int kt = 0; kt <= qt; ++kt) {
    // ---- stage K tile and V^T tile (each wave issues 8 gld16) ----
    if (w == 0) {
      #pragma unroll
      for (int c = 0; c < 2; ++c)
        #pragma unroll
        for (int kb = 0; kb < 4; ++kb)
          gld16(Kh + ((size_t)h * SEQ + kt * 64 + kb * 16 + (lane >> 2)) * 64 + c * 32 + (lane & 3) * 8,
                &Ksh[c][kb * 16][0]);
    } else if (w == 1) {
      #pragma unroll
      for (int c = 0; c < 2; ++c)
        #pragma unroll
        for (int kb = 0; kb < 4; ++kb)
          gld16(Kl + ((size_t)h * SEQ + kt * 64 + kb * 16 + (lane >> 2)) * 64 + c * 32 + (lane & 3) * 8,
                &Ksl[c][kb * 16][0]);
    } else if (w == 2) {
      #pragma unroll
      for (int g = 0; g < 4; ++g)
        #pragma unroll
        for (int hd = 0; hd < 2; ++hd)
          gld16(Vth + ((size_t)h * HDIM + hd * 32 + (lane >> 1)) * SEQ + kt * 64 + g * 16 + (lane & 1) * 8,
                &Vsh[g][hd * 32][0]);
    } else {
      #pragma unroll
      for (int g = 0; g < 4; ++g)
        #pragma unroll
        for (int hd = 0; hd < 2; ++hd)
          gld16(Vtl + ((size_t)h * HDIM + hd * 32 + (lane >> 1)) * SEQ + kt * 64 + g * 16 + (lane & 1) * 8,
                &Vsl[g][hd * 32][0]);
    }
    __syncthreads();

    // ---- S = Q K^T (split-f16, 3 MFMAs per tile-pair) ----
    f32x4 s4[4];
    #pragma unroll
    for (int nt = 0; nt < 4; ++nt) s4[nt] = (f32x4)(0.f);
    #pragma unroll
    for (int c = 0; c < 2; ++c) {
      const f16x8 qhc = c ? qh1 : qh0;
      const f16x8 qlc = c ? ql1 : ql0;
      #pragma unroll
      for (int nt = 0; nt < 4; ++nt) {
        const f16x8 kh8 = *(const f16x8*)&Ksh[c][nt * 16 + m_][quad * 8];
        const f16x8 kl8 = *(const f16x8*)&Ksl[c][nt * 16 + m_][quad * 8];
        s4[nt] = __builtin_amdgcn_mfma_f32_16x16x32_f16(qlc, kh8, s4[nt], 0, 0, 0);
        s4[nt] = __builtin_amdgcn_mfma_f32_16x16x32_f16(qhc, kl8, s4[nt], 0, 0, 0);
        s4[nt] = __builtin_amdgcn_mfma_f32_16x16x32_f16(qhc, kh8, s4[nt], 0, 0, 0);
      }
    }
    // ---- causal mask on diagonal tile ----
    if (kt == qt) {
      #pragma unroll
      for (int nt = 0; nt < 4; ++nt)
        #pragma unroll
        for (int r = 0; r < 4; ++r)
          if (nt * 16 + m_ > w * 16 + quad * 4 + r) s4[nt][r] = -1e30f;
    }
    // ---- online softmax (registers + shuffles; rows live on 16-lane groups) ----
    float mx[4];
    #pragma unroll
    for (int r = 0; r < 4; ++r)
      mx[r] = fmaxf(fmaxf(s4[0][r], s4[1][r]), fmaxf(s4[2][r], s4[3][r]));
    #pragma unroll
    for (int msk = 1; msk < 16; msk <<= 1)
      #pragma unroll
      for (int r = 0; r < 4; ++r) mx[r] = fmaxf(mx[r], __shfl_xor(mx[r], msk));
    float al[4];
    #pragma unroll
    for (int r = 0; r < 4; ++r) {
      const float mn = fmaxf(m_r[r], mx[r]);
      al[r] = expf(m_r[r] - mn);
      m_r[r] = mn;
    }
    float rs[4] = {0.f, 0.f, 0.f, 0.f};
    #pragma unroll
    for (int nt = 0; nt < 4; ++nt) {
      #pragma unroll
      for (int r = 0; r < 4; ++r) {
        const float p = expf(s4[nt][r] - m_r[r]);
        rs[r] += p;
        const _Float16 ph = (_Float16)p;
        Ph[w][quad * 4 + r][nt * 16 + m_] = ph;
        Pl[w][quad * 4 + r][nt * 16 + m_] = (_Float16)(p - (float)ph);
      }
    }
    #pragma unroll
    for (int msk = 1; msk < 16; msk <<= 1)
      #pragma unroll
      for (int r = 0; r < 4; ++r) rs[r] += __shfl_xor(rs[r], msk);
    #pragma unroll
    for (int r = 0; r < 4; ++r) l_r[r] = l_r[r] * al[r] + rs[r];
    #pragma unroll
    for (int nt = 0; nt < 4; ++nt)
      #pragma unroll
      for (int r = 0; r < 4; ++r) o[nt][r] *= al[r];

    // ---- O += P V (split-f16) ----
    #pragma unroll
    for (int c = 0; c < 2; ++c) {
      const f16x8 pah = *(const f16x8*)&Ph[w][m_][c * 32 + quad * 8];
      const f16x8 pal = *(const f16x8*)&Pl[w][m_][c * 32 + quad * 8];
      #pragma unroll
      for (int nt = 0; nt < 4; ++nt) {
        const f16x8 vh8 = *(const f16x8*)&Vsh[c * 2 + (quad >> 1)][nt * 16 + m_][(quad & 1) * 8];
        const f16x8 vl8 = *(const f16x8*)&Vsl[c * 2 + (quad >> 1)][nt * 16 + m_][(quad & 1) * 8];
        o[nt] = __builtin_amdgcn_mfma_f32_16x16x32_f16(pal, vh8, o[nt], 0, 0, 0);
        o[nt] = __builtin_amdgcn_mfma_f32_16x16x32_f16(pah, vl8, o[nt], 0, 0, 0);
        o[nt] = __builtin_amdgcn_mfma_f32_16x16x32_f16(pah, vh8, o[nt], 0, 0, 0);
      }
    }
    __syncthreads();
  }

  // ---- epilogue: O/l, split to f16 hi/lo ----
  float inv[4];
  #pragma unroll
  for (int r = 0; r < 4; ++r) inv[r] = 1.0f / l_r[r];
  #pragma unroll
  for (int nt = 0; nt < 4; ++nt)
    #pragma unroll
    for (int r = 0; r < 4; ++r) {
      const float v = o[nt][r] * inv[r];
      const _Float16 hi = (_Float16)v;
      const size_t idx = ((size_t)(q0 + quad * 4 + r)) * HID + h * HDIM + nt * 16 + m_;
      attn_h[idx] = hi;
      attn_l[idx] = (_Float16)(v - (float)hi);
    }
}

// ---------------- router (fp32, discrete top-2 must match reference) ----------------
__global__ __launch_bounds__(64) void k_router(const float* __restrict__ xn2,
                                               const float* __restrict__ rw,
                                               int* __restrict__ tidx,
                                               float* __restrict__ tw) {
  const int n = blockIdx.x, lane = threadIdx.x;
  float lg[8] = {0.f,0.f,0.f,0.f,0.f,0.f,0.f,0.f};
  #pragma unroll
  for (int i = 0; i < 4; ++i) {
    float4 xv = ((const float4*)(xn2 + (size_t)n * HID))[lane + 64 * i];
    #pragma unroll
    for (int e = 0; e < 8; ++e) {
      float4 wv = ((const float4*)(rw + (size_t)e * HID))[lane + 64 * i];
      lg[e] += xv.x*wv.x + xv.y*wv.y + xv.z*wv.z + xv.w*wv.w;
    }
  }
  #pragma unroll
  for (int e = 0; e < 8; ++e) {
    #pragma unroll
    for (int off = 32; off; off >>= 1) lg[e] += __shfl_xor(lg[e], off);
  }
  if (lane == 0) {
    int e1 = 0; float l1 = lg[0];
    #pragma unroll
    for (int e = 1; e < 8; ++e) if (lg[e] > l1) { l1 = lg[e]; e1 = e; }
    int e2 = -1; float l2 = -INFINITY;
    #pragma unroll
    for (int e = 0; e < 8; ++e) if (e != e1 && lg[e] > l2) { l2 = lg[e]; e2 = e; }
    const float w1 = 1.0f / (1.0f + expf(l2 - l1));
    tidx[n * 2] = e1; tidx[n * 2 + 1] = e2;
    tw[n * 2] = w1;  tw[n * 2 + 1] = 1.0f - w1;
  }
}

// ---------------- capacity scan + aux loss ----------------
__global__ __launch_bounds__(512) void k_scan(const int* __restrict__ tidx,
                                              int* __restrict__ slotk,
                                              int* __restrict__ perm,
                                              int* __restrict__ counts,
                                              float* __restrict__ aux_out) {
  const int t = threadIdx.x;
  const int e = t >> 6, lane = t & 63;
  __shared__ int cls[8];
  int offset = 0;
  for (int chunk = 0; chunk < SEQ / 64; ++chunk) {
    const int n = chunk * 64 + lane;
    const int i0 = tidx[n * 2], i1 = tidx[n * 2 + 1];
    const bool bit = (i0 == e) || (i1 == e);
    const unsigned long long mask = __ballot(bit);
    const int pos = offset + __popcll(mask & ((1ull << lane) - 1ull));
    if (bit) {
      const int kk = (i0 == e) ? 0 : 1;
      slotk[n * 2 + kk] = pos;
      if (pos < CAPE) perm[e * CAPE + pos] = n;
    }
    offset += __popcll(mask);
  }
  if (lane == 0) { counts[e] = offset; cls[e] = offset; }
  __syncthreads();
  if (t == 0) {
    float mean = 0.f;
    for (int i = 0; i < 8; ++i) mean += (float)cls[i];
    mean /= (8.0f * (float)SEQ);
    float var = 0.f;
    for (int i = 0; i < 8; ++i) {
      const float f = (float)cls[i] / (float)SEQ;
      var += (f - mean) * (f - mean);
    }
    var /= 7.0f;
    aux_out[0] = var * 8.0f;
  }
}

// ---------------- MoE gate/up: bf16 MFMA ----------------
__global__ __launch_bounds__(256, 2) void k_moe_gu(const __bf16* __restrict__ X,
                                                   const __bf16* __restrict__ Wg,
                                                   const __bf16* __restrict__ Wu,
                                                   const int* __restrict__ perm,
                                                   const int* __restrict__ counts,
                                                   __bf16* __restrict__ act) {
  const int e = blockIdx.z;
  const int rows = min(counts[e], CAPE);
  const int m0 = blockIdx.y * 128;
  if (m0 >= rows) return;
  const int n0 = blockIdx.x * 128;
  __shared__ __align__(16) __bf16 As[128 * 32];
  __shared__ __align__(16) __bf16 Bgs[128 * 32];
  __shared__ __align__(16) __bf16 Bus[128 * 32];
  const int t = threadIdx.x;
  const int lane = t & 63, w = t >> 6;
  const int wr = w & 1, wc = w >> 1;
  const int sr = t >> 2;
  const int sk = (t & 3) * 8;
  const int gr0 = m0 + sr, gr1 = m0 + 64 + sr;
  const size_t arow0 = (size_t)((gr0 < rows) ? perm[e * CAPE + gr0] : 0) * HID;
  const size_t arow1 = (size_t)((gr1 < rows) ? perm[e * CAPE + gr1] : 0) * HID;
  const __bf16* gB = Wg + (size_t)e * IDIM * HID;
  const __bf16* uB = Wu + (size_t)e * IDIM * HID;
  const size_t brow0 = (size_t)(n0 + sr) * HID, brow1 = (size_t)(n0 + 64 + sr) * HID;
  f32x4 accg[4][4], accu[4][4];
  #pragma unroll
  for (int i = 0; i < 4; ++i)
    #pragma unroll
    for (int j = 0; j < 4; ++j) { accg[i][j] = (f32x4)(0.f); accu[i][j] = (f32x4)(0.f); }

  for (int kk = 0; kk < HID; kk += 32) {
    gld16(X + arow0 + kk + sk, As + w * 512);
    gld16(X + arow1 + kk + sk, As + 2048 + w * 512);
    gld16(gB + brow0 + kk + sk, Bgs + w * 512);
    gld16(gB + brow1 + kk + sk, Bgs + 2048 + w * 512);
    gld16(uB + brow0 + kk + sk, Bus + w * 512);
    gld16(uB + brow1 + kk + sk, Bus + 2048 + w * 512);
    __syncthreads();
    bf16x8 a[4], bg[4], bu[4];
    #pragma unroll
    for (int i = 0; i < 4; ++i) {
      const int fo = (lane & 15) * 32 + (lane >> 4) * 8;
      a[i]  = *(const bf16x8*)&As[(wr * 64 + i * 16) * 32 + fo];
      bg[i] = *(const bf16x8*)&Bgs[(wc * 64 + i * 16) * 32 + fo];
      bu[i] = *(const bf16x8*)&Bus[(wc * 64 + i * 16) * 32 + fo];
    }
    #pragma unroll
    for (int i = 0; i < 4; ++i)
      #pragma unroll
      for (int j = 0; j < 4; ++j) {
        accg[i][j] = __builtin_amdgcn_mfma_f32_16x16x32_bf16(a[i], bg[j], accg[i][j], 0, 0, 0);
        accu[i][j] = __builtin_amdgcn_mfma_f32_16x16x32_bf16(a[i], bu[j], accu[i][j], 0, 0, 0);
      }
    __syncthreads();
  }
  const int cb = lane & 15, rb = (lane >> 4) * 4;
  #pragma unroll
  for (int i = 0; i < 4; ++i)
    #pragma unroll
    for (int r = 0; r < 4; ++r) {
      const int rr = m0 + wr * 64 + i * 16 + rb + r;
      if (rr < rows) {
        #pragma unroll
        for (int j = 0; j < 4; ++j) {
          const float g = accg[i][j][r], u = accu[i][j][r];
          const float v = g / (1.f + expf(-g)) * u;
          act[((size_t)e * CAPE + rr) * IDIM + n0 + wc * 64 + j * 16 + cb] = (__bf16)v;
        }
      }
    }
}

// ---------------- MoE down: bf16 MFMA ----------------
__global__ __launch_bounds__(256, 2) void k_moe_down(const __bf16* __restrict__ act,
                                                     const __bf16* __restrict__ Wd,
                                                     const int* __restrict__ counts,
                                                     float* __restrict__ y) {
  const int e = blockIdx.z;
  const int rows = min(counts[e], CAPE);
  const int m0 = blockIdx.y * 128;
  if (m0 >= rows) return;
  const int n0 = blockIdx.x * 128;
  __shared__ __align__(16) __bf16 As[128 * 32];
  __shared__ __align__(16) __bf16 Bs[128 * 32];
  const int t = threadIdx.x;
  const int lane = t & 63, w = t >> 6;
  const int wr = w & 1, wc = w >> 1;
  const int sr = t >> 2;
  const int sk = (t & 3) * 8;
  const __bf16* Ab = act + ((size_t)e * CAPE) * IDIM;
  const __bf16* Bb = Wd + (size_t)e * HID * IDIM;
  const size_t arow0 = (size_t)(m0 + sr) * IDIM, arow1 = (size_t)(m0 + 64 + sr) * IDIM;
  const size_t brow0 = (size_t)(n0 + sr) * IDIM, brow1 = (size_t)(n0 + 64 + sr) * IDIM;
  f32x4 acc[4][4];
  #pragma unroll
  for (int i = 0; i < 4; ++i)
    #pragma unroll
    for (int j = 0; j < 4; ++j) acc[i][j] = (f32x4)(0.f);

  for (int kk = 0; kk < IDIM; kk += 32) {
    gld16(Ab + arow0 + kk + sk, As + w * 512);
    gld16(Ab + arow1 + kk + sk, As + 2048 + w * 512);
    gld16(Bb + brow0 + kk + sk, Bs + w * 512);
    gld16(Bb + brow1 + kk + sk, Bs + 2048 + w * 512);
    __syncthreads();
    bf16x8 a[4], b[4];
    #pragma unroll
    for (int i = 0; i < 4; ++i) {
      const int fo = (lane & 15) * 32 + (lane >> 4) * 8;
      a[i] = *(const bf16x8*)&As[(wr * 64 + i * 16) * 32 + fo];
      b[i] = *(const bf16x8*)&Bs[(wc * 64 + i * 16) * 32 + fo];
    }
    #pragma unroll
    for (int i = 0; i < 4; ++i)
      #pragma unroll
      for (int j = 0; j < 4; ++j)
        acc[i][j] = __builtin_amdgcn_mfma_f32_16x16x32_bf16(a[i], b[j], acc[i][j], 0, 0, 0);
    __syncthreads();
  }
  const int cb = lane & 15, rb = (lane >> 4) * 4;
  #pragma unroll
  for (int i = 0; i < 4; ++i)
    #pragma unroll
    for (int r = 0; r < 4; ++r) {
      const int rr = m0 + wr * 64 + i * 16 + rb + r;
      if (rr < rows) {
        #pragma unroll
        for (int j = 0; j < 4; ++j)
          y[((size_t)e * CAPE + rr) * HID + n0 + wc * 64 + j * 16 + cb] = acc[i][j][r];
      }
    }
}

// ---------------- combine ----------------
__global__ __launch_bounds__(256) void k_combine(const float* __restrict__ x1,
                                                 const float* __restrict__ y,
                                                 const int* __restrict__ tidx,
                                                 const float* __restrict__ tw,
                                                 const int* __restrict__ slotk,
                                                 float* __restrict__ out) {
  const int n = blockIdx.x, t = threadIdx.x;
  float4 acc = ((const float4*)(x1 + (size_t)n * HID))[t];
  #pragma unroll
  for (int k = 0; k < 2; ++k) {
    const int slot = slotk[n * 2 + k];
    if (slot < CAPE) {
      const int e = tidx[n * 2 + k];
      const float w = tw[n * 2 + k];
      float4 v = ((const float4*)(y + ((size_t)e * CAPE + slot) * HID))[t];
      acc.x += w * v.x; acc.y += w * v.y; acc.z += w * v.z; acc.w += w * v.w;
    }
  }
  ((float4*)(out + (size_t)n * HID))[t] = acc;
}

extern "C" void kernel_launch(void* const* d_in, const int* in_sizes, int n_in,
                              void* d_out, int out_size, void* d_ws, size_t ws_size,
                              hipStream_t stream) {
  const float* x     = (const float*)d_in[0];
  const float* anw   = (const float*)d_in[1];
  const float* qkv_w = (const float*)d_in[2];
  const float* o_w   = (const float*)d_in[3];
  const float* fnw   = (const float*)d_in[4];
  const float* rw    = (const float*)d_in[5];
  const float* wg    = (const float*)d_in[6];
  const float* wu    = (const float*)d_in[7];
  const float* wd    = (const float*)d_in[8];
  (void)in_sizes; (void)n_in; (void)out_size; (void)ws_size;
  float* out = (float*)d_out;

  float* ws = (float*)d_ws;
  size_t off = 0;
  float* qkv  = ws + off; off += (size_t)SEQ * QKVW;
  float* x1   = ws + off; off += (size_t)SEQ * HID;
  float* xn2  = ws + off; off += (size_t)SEQ * HID;
  float* ybuf = ws + off; off += (size_t)NEXP * CAPE * HID;
  float* tw   = ws + off; off += SEQ * 2;
  int* tidx   = (int*)(ws + off); off += SEQ * 2;
  int* slotk  = (int*)(ws + off); off += SEQ * 2;
  int* perm   = (int*)(ws + off); off += NEXP * CAPE;
  int* counts = (int*)(ws + off); off += 16;
  // 2-byte element region
  __bf16* bfbase = (__bf16*)(ws + off);
  size_t boff = 0;
  __bf16* xn2_bf = bfbase + boff; boff += (size_t)SEQ * HID;
  __bf16* wg_bf  = bfbase + boff; boff += (size_t)NEXP * IDIM * HID;
  __bf16* wu_bf  = bfbase + boff; boff += (size_t)NEXP * IDIM * HID;
  __bf16* wd_bf  = bfbase + boff; boff += (size_t)NEXP * HID * IDIM;
  __bf16* act_bf = bfbase + boff; boff += (size_t)NEXP * CAPE * IDIM;
  _Float16* f16base = (_Float16*)(bfbase + boff);
  size_t foff = 0;
  _Float16* xn_h   = f16base + foff; foff += (size_t)SEQ * HID;
  _Float16* xn_l   = f16base + foff; foff += (size_t)SEQ * HID;
  _Float16* qkvw_h = f16base + foff; foff += (size_t)QKVW * HID;
  _Float16* qkvw_l = f16base + foff; foff += (size_t)QKVW * HID;
  _Float16* attn_h = f16base + foff; foff += (size_t)SEQ * HID;
  _Float16* attn_l = f16base + foff; foff += (size_t)SEQ * HID;
  _Float16* ow_h   = f16base + foff; foff += (size_t)HID * HID;
  _Float16* ow_l   = f16base + foff; foff += (size_t)HID * HID;
  _Float16* Qhb    = f16base + foff; foff += (size_t)NHEAD * SEQ * HDIM;
  _Float16* Qlb    = f16base + foff; foff += (size_t)NHEAD * SEQ * HDIM;
  _Float16* Khb    = f16base + foff; foff += (size_t)NHEAD * SEQ * HDIM;
  _Float16* Klb    = f16base + foff; foff += (size_t)NHEAD * SEQ * HDIM;
  _Float16* Vthb   = f16base + foff; foff += (size_t)NHEAD * SEQ * HDIM;
  _Float16* Vtlb   = f16base + foff; foff += (size_t)NHEAD * SEQ * HDIM;

  const long nw8 = (long)NEXP * IDIM * HID / 8;
  const int cvtGrid = (int)((nw8 + 255) / 256);
  k_cvt_bf16<<<cvtGrid, 256, 0, stream>>>(wg, wg_bf, nw8);
  k_cvt_bf16<<<cvtGrid, 256, 0, stream>>>(wu, wu_bf, nw8);
  k_cvt_bf16<<<cvtGrid, 256, 0, stream>>>(wd, wd_bf, nw8);
  k_split_f16<<<(QKVW * HID / 8 + 255) / 256, 256, 0, stream>>>(qkv_w, qkvw_h, qkvw_l, QKVW * HID / 8);
  k_split_f16<<<(HID * HID / 8 + 255) / 256, 256, 0, stream>>>(o_w, ow_h, ow_l, HID * HID / 8);

  k_rmsnorm<<<SEQ, 256, 0, stream>>>(x, anw, nullptr, nullptr, xn_h, xn_l);
  k_lin<<<dim3(QKVW / 128, SEQ / 128), 256, 0, stream>>>(xn_h, xn_l, qkvw_h, qkvw_l, nullptr, qkv, QKVW, HID);
  k_prep<<<dim3(NHEAD, SEQ / 64), 256, 0, stream>>>(qkv, Qhb, Qlb, Khb, Klb, Vthb, Vtlb);
  k_attn2<<<dim3(NHEAD, SEQ / 64), 256, 0, stream>>>(Qhb, Qlb, Khb, Klb, Vthb, Vtlb, attn_h, attn_l);
  k_lin<<<dim3(HID / 128, SEQ / 128), 256, 0, stream>>>(attn_h, attn_l, ow_h, ow_l, x, x1, HID, HID);
  k_rmsnorm<<<SEQ, 256, 0, stream>>>(x1, fnw, xn2, xn2_bf, nullptr, nullptr);
  k_router<<<SEQ, 64, 0, stream>>>(xn2, rw, tidx, tw);
  k_scan<<<1, 512, 0, stream>>>(tidx, slotk, perm, counts, out + (size_t)SEQ * HID);
  k_moe_gu<<<dim3(IDIM / 128, CAPE / 128, NEXP), 256, 0, stream>>>(xn2_bf, wg_bf, wu_bf, perm, counts, act_bf);
  k_moe_down<<<dim3(HID / 128, CAPE / 128, NEXP), 256, 0, stream>>>(act_bf, wd_bf, counts, ybuf);
  k_combine<<<SEQ, 256, 0, stream>>>(x1, ybuf, tidx, tw, slotk, out);
}